// Round 1
// 9048.138 us; speedup vs baseline: 1.1943x; 1.1943x over previous
//
#include <hip/hip_runtime.h>
#include <cstdint>
#include <cstddef>

#define N_NODES 20000
#define N_EDGES 640000

typedef short short8 __attribute__((ext_vector_type(8)));
typedef float floatx4 __attribute__((ext_vector_type(4)));

__device__ __forceinline__ ushort f2bf(float f) {
    uint32_t u = __float_as_uint(f);
    uint32_t r = (u + 0x7fff + ((u >> 16) & 1)) >> 16;
    return (ushort)r;
}
__device__ __forceinline__ float bf2f(ushort u) {
    return __uint_as_float(((uint32_t)u) << 16);
}

// ---------------------------------------------------------------- utilities
__global__ __launch_bounds__(256) void zero_i32(int* __restrict__ p, int n) {
    int i = blockIdx.x * 256 + threadIdx.x;
    if (i < n) p[i] = 0;
}

// weight pre-transpose + bf16 convert: W[K][Nc] fp32 -> Bt[Nc][Kp] bf16 (zero pad)
__global__ __launch_bounds__(256) void transpose_w(const float* __restrict__ W,
                                                   ushort* __restrict__ Bt,
                                                   int K, int Nc, int Kp) {
    int idx = blockIdx.x * 256 + threadIdx.x;
    if (idx >= Nc * Kp) return;
    int n = idx / Kp, k = idx % Kp;
    Bt[idx] = (k < K) ? f2bf(W[(size_t)k * Nc + n]) : (ushort)0;
}

// ---------------------------------------------------------------- CSR build
__global__ __launch_bounds__(256) void hist_kernel(const int* __restrict__ rows,
                                                   int* __restrict__ counts) {
    int e = blockIdx.x * 256 + threadIdx.x;
    if (e < N_EDGES) atomicAdd(&counts[rows[e]], 1);
}

__global__ __launch_bounds__(1024) void scan_kernel(const int* __restrict__ counts,
                                                    int* __restrict__ row_ptr) {
    __shared__ int part[1024];
    const int CH = 20;
    int tid = threadIdx.x;
    int t0 = tid * CH;
    int s = 0;
    for (int i = 0; i < CH; ++i) {
        int p = t0 + i;
        if (p < N_NODES) s += counts[p];
    }
    part[tid] = s;
    __syncthreads();
    for (int off = 1; off < 1024; off <<= 1) {
        int v = (tid >= off) ? part[tid - off] : 0;
        __syncthreads();
        if (tid >= off) part[tid] += v;
        __syncthreads();
    }
    int base = (tid == 0) ? 0 : part[tid - 1];
    for (int i = 0; i < CH; ++i) {
        int p = t0 + i;
        if (p < N_NODES) {
            row_ptr[p] = base;
            base += counts[p];
            if (p == N_NODES - 1) row_ptr[N_NODES] = base;
        }
    }
}

__global__ __launch_bounds__(256) void fill_kernel(const int* __restrict__ rows,
                                                   const int* __restrict__ cols,
                                                   const float* __restrict__ vals,
                                                   const int* __restrict__ row_ptr,
                                                   int* __restrict__ fillctr,
                                                   int* __restrict__ cols_s,
                                                   float* __restrict__ vals_s) {
    int e = blockIdx.x * 256 + threadIdx.x;
    if (e < N_EDGES) {
        int r = rows[e];
        int pos = atomicAdd(&fillctr[r], 1);
        int idx = row_ptr[r] + pos;
        cols_s[idx] = cols[e];
        vals_s[idx] = vals[e];
    }
}

// ---------------------------------------------------------------- MFMA GEMM
// C[M,Nc] = act(A[M,K] @ B[K,Nc] + bias).
// A fp32 (A) OR bf16 (Ab). B pre-transposed bf16 [Nc][Kp].
// Output: Cb!=null -> bf16 else fp32. act: 1=relu, 2=leaky(0.2)+elu.
// split=1 (fp32 A only): A staged as bf16 hi+lo, two MFMAs -> ~fp32 accuracy.
// Block 256 thr = 4 waves (2x2), tile 128x128, K-step 32, mfma_f32_16x16x32_bf16.
// A frag: lane holds A[m=lane&15][k=quad*8+j]; C/D: col=lane&15,row=quad*4+reg (m89/m91).
__global__ __launch_bounds__(256) void mfma_gemm(
    const float* __restrict__ A, const ushort* __restrict__ Ab,
    const ushort* __restrict__ Bt,
    const float* __restrict__ bias, float* __restrict__ Cf,
    ushort* __restrict__ Cb, int M, int K, int Nc, int Kp, int act, int split) {
    __shared__ __align__(16) ushort As[128][40];  // +8 pad breaks bank aliasing
    __shared__ __align__(16) ushort Al[128][40];  // lo part (split mode)
    __shared__ __align__(16) ushort Bs[128][40];

    int tid = threadIdx.x;
    int wave = tid >> 6, lane = tid & 63;
    int wr = (wave >> 1) * 64, wc = (wave & 1) * 64;
    int m16 = lane & 15, quad = lane >> 4;
    int row0 = blockIdx.y * 128, col0 = blockIdx.x * 128;

    floatx4 acc[4][4] = {};
    int KT = (K + 31) >> 5;
    bool k4 = (K & 3) == 0;

    for (int kt = 0; kt < KT; ++kt) {
        int k0 = kt << 5;
        // --- stage A ---
        {
            int r = tid >> 3;
            int kq = (tid & 7) << 2;
#pragma unroll
            for (int p = 0; p < 4; ++p) {
                int rr = r + p * 32;
                int grow = row0 + rr;
                int gk = k0 + kq;
                if (Ab) {
                    // bf16 A input (no split)
                    ushort4 hi = {0, 0, 0, 0};
                    if (grow < M) {
                        const ushort* ap = Ab + (size_t)grow * K;
                        if (gk + 3 < K) {
                            hi = *(const ushort4*)(ap + gk);
                        } else {
                            if (gk < K) hi.x = ap[gk];
                            if (gk + 1 < K) hi.y = ap[gk + 1];
                            if (gk + 2 < K) hi.z = ap[gk + 2];
                            if (gk + 3 < K) hi.w = ap[gk + 3];
                        }
                    }
                    *(ushort4*)&As[rr][kq] = hi;
                } else {
                    float v[4] = {0.f, 0.f, 0.f, 0.f};
                    if (grow < M) {
                        const float* ap = A + (size_t)grow * K;
                        if (k4 && gk + 3 < K) {
                            float4 f = *(const float4*)(ap + gk);
                            v[0] = f.x; v[1] = f.y; v[2] = f.z; v[3] = f.w;
                        } else {
                            if (gk < K) v[0] = ap[gk];
                            if (gk + 1 < K) v[1] = ap[gk + 1];
                            if (gk + 2 < K) v[2] = ap[gk + 2];
                            if (gk + 3 < K) v[3] = ap[gk + 3];
                        }
                    }
                    ushort4 hi;
                    hi.x = f2bf(v[0]); hi.y = f2bf(v[1]);
                    hi.z = f2bf(v[2]); hi.w = f2bf(v[3]);
                    *(ushort4*)&As[rr][kq] = hi;
                    if (split) {
                        ushort4 lo;
                        lo.x = f2bf(v[0] - bf2f(hi.x));
                        lo.y = f2bf(v[1] - bf2f(hi.y));
                        lo.z = f2bf(v[2] - bf2f(hi.z));
                        lo.w = f2bf(v[3] - bf2f(hi.w));
                        *(ushort4*)&Al[rr][kq] = lo;
                    }
                }
            }
        }
        // --- stage B (already bf16, [Nc][Kp], Kp%32==0 so 16B aligned) ---
        {
            int n = tid >> 2;
            int ch = (tid & 3) << 3;
#pragma unroll
            for (int p = 0; p < 2; ++p) {
                int nn = n + p * 64;
                int gcol = col0 + nn;
                if (gcol < Nc) {
                    *(uint4*)&Bs[nn][ch] =
                        *(const uint4*)&Bt[(size_t)gcol * Kp + k0 + ch];
                } else {
                    uint4 z = {0, 0, 0, 0};
                    *(uint4*)&Bs[nn][ch] = z;
                }
            }
        }
        __syncthreads();
        // --- MFMA ---
        short8 a[4], b[4];
        int ko = quad * 8;
#pragma unroll
        for (int i = 0; i < 4; ++i) a[i] = *(short8*)&As[wr + i * 16 + m16][ko];
#pragma unroll
        for (int j = 0; j < 4; ++j) b[j] = *(short8*)&Bs[wc + j * 16 + m16][ko];
        if (split) {
            short8 al[4];
#pragma unroll
            for (int i = 0; i < 4; ++i) al[i] = *(short8*)&Al[wr + i * 16 + m16][ko];
#pragma unroll
            for (int i = 0; i < 4; ++i)
#pragma unroll
                for (int j = 0; j < 4; ++j)
                    acc[i][j] = __builtin_amdgcn_mfma_f32_16x16x32_bf16(
                        al[i], b[j], acc[i][j], 0, 0, 0);
        }
#pragma unroll
        for (int i = 0; i < 4; ++i)
#pragma unroll
            for (int j = 0; j < 4; ++j)
                acc[i][j] = __builtin_amdgcn_mfma_f32_16x16x32_bf16(
                    a[i], b[j], acc[i][j], 0, 0, 0);
        __syncthreads();
    }

    // --- epilogue ---
#pragma unroll
    for (int i = 0; i < 4; ++i) {
        int rbase = row0 + wr + i * 16 + quad * 4;
#pragma unroll
        for (int j = 0; j < 4; ++j) {
            int gcol = col0 + wc + j * 16 + m16;
            if (gcol >= Nc) continue;
            float bv = bias ? bias[gcol] : 0.f;
#pragma unroll
            for (int r = 0; r < 4; ++r) {
                int grow = rbase + r;
                if (grow >= M) continue;
                float v = acc[i][j][r] + bv;
                if (act == 1) v = v > 0.f ? v : 0.f;
                else if (act == 2) v = v > 0.f ? v : (expf(0.2f * v) - 1.0f);
                if (Cb) Cb[(size_t)grow * Nc + gcol] = f2bf(v);
                else Cf[(size_t)grow * Nc + gcol] = v;
            }
        }
    }
}

// ---------------------------------------------------------------- small vector GEMM
// kept only for the 10x10 matmuls (z, d0)
__global__ __launch_bounds__(256) void gemm_small(
    const float* __restrict__ A, const float* __restrict__ B,
    const float* __restrict__ bias, float* __restrict__ C,
    int M, int K, int Nc, int act) {
    int row = blockIdx.x * 8 + (threadIdx.x >> 5);
    int c = threadIdx.x & 31;
    if (row >= M || c >= Nc) return;
    float acc = bias ? bias[c] : 0.f;
    for (int k = 0; k < K; ++k) acc += A[(size_t)row * K + k] * B[(size_t)k * Nc + c];
    if (act) acc = acc > 0.f ? acc : 0.f;
    C[(size_t)row * Nc + c] = acc;
}

// ---------------------------------------------------------------- SpMM + act (bf16)
// t[r,f] = elu(leaky(sum vals*sup[col,f])); sup/t bf16, 2 features per thread.
__global__ __launch_bounds__(256) void spmm_act_bf(const ushort* __restrict__ sup,
                                                   const int* __restrict__ row_ptr,
                                                   const int* __restrict__ cols_s,
                                                   const float* __restrict__ vals_s,
                                                   ushort* __restrict__ t, int C) {
    int r = blockIdx.x;
    int f0 = blockIdx.y * 512 + threadIdx.x * 2;
    int s = row_ptr[r], e = row_ptr[r + 1];
    float a0 = 0.f, a1 = 0.f;
    if (f0 < C) {
        for (int i = s; i < e; ++i) {
            float v = vals_s[i];
            int c = cols_s[i];
            uint u = *(const uint*)&sup[(size_t)c * C + f0];
            a0 += v * bf2f((ushort)(u & 0xffff));
            a1 += v * bf2f((ushort)(u >> 16));
        }
        float r0 = a0 > 0.f ? a0 : (expf(0.2f * a0) - 1.f);
        float r1 = a1 > 0.f ? a1 : (expf(0.2f * a1) - 1.f);
        ushort2 w;
        w.x = f2bf(r0);
        w.y = f2bf(r1);
        *(ushort2*)&t[(size_t)r * C + f0] = w;
    }
}

// ---------------------------------------------------------------- SpMM gather only (bf16 in, fp32 out)
// agg[r,f] = sum vals*h[col,f] ; used for layer-3 spmm-first: A@(h@W) == (A@h)@W
__global__ __launch_bounds__(256) void spmm_gather_bf(const ushort* __restrict__ h,
                                                      const int* __restrict__ row_ptr,
                                                      const int* __restrict__ cols_s,
                                                      const float* __restrict__ vals_s,
                                                      float* __restrict__ agg, int C) {
    int r = blockIdx.x;
    int f0 = blockIdx.y * 512 + threadIdx.x * 2;
    if (f0 >= C) return;
    int s = row_ptr[r], e = row_ptr[r + 1];
    float a0 = 0.f, a1 = 0.f;
    for (int i = s; i < e; ++i) {
        float v = vals_s[i];
        int c = cols_s[i];
        uint u = *(const uint*)&h[(size_t)c * C + f0];
        a0 += v * bf2f((ushort)(u & 0xffff));
        a1 += v * bf2f((ushort)(u >> 16));
    }
    float2 w;
    w.x = a0;
    w.y = a1;
    *(float2*)&agg[(size_t)r * C + f0] = w;
}

// ---------------------------------------------------------------- SpMM + act (fp32, fea branch)
__global__ __launch_bounds__(256) void spmm_act_f(const float* __restrict__ sup,
                                                  const int* __restrict__ row_ptr,
                                                  const int* __restrict__ cols_s,
                                                  const float* __restrict__ vals_s,
                                                  float* __restrict__ t, int C) {
    int r = blockIdx.x;
    int f = blockIdx.y * 256 + threadIdx.x;
    int s = row_ptr[r], e = row_ptr[r + 1];
    float acc = 0.f;
    for (int i = s; i < e; ++i) {
        float v = vals_s[i];
        int c = cols_s[i];
        if (f < C) acc += v * sup[(size_t)c * C + f];
    }
    if (f < C) {
        float a = acc;
        t[(size_t)r * C + f] = a > 0.f ? a : (expf(0.2f * a) - 1.0f);
    }
}

// ---------------------------------------------------------------- SpMM gather only (fp32)
__global__ __launch_bounds__(256) void spmm_gather_f(const float* __restrict__ h,
                                                     const int* __restrict__ row_ptr,
                                                     const int* __restrict__ cols_s,
                                                     const float* __restrict__ vals_s,
                                                     float* __restrict__ agg, int C) {
    int r = blockIdx.x;
    int f = blockIdx.y * 256 + threadIdx.x;
    int s = row_ptr[r], e = row_ptr[r + 1];
    float acc = 0.f;
    for (int i = s; i < e; ++i) {
        float v = vals_s[i];
        int c = cols_s[i];
        if (f < C) acc += v * h[(size_t)c * C + f];
    }
    if (f < C) agg[(size_t)r * C + f] = acc;
}

// ---------------------------------------------------------------- BatchNorm (bf16 t)
__global__ __launch_bounds__(256) void col_stats(const ushort* __restrict__ t,
                                                 float* __restrict__ sum,
                                                 float* __restrict__ sumsq, int C) {
    int c = blockIdx.x * 256 + threadIdx.x;
    int r0 = blockIdx.y * 500;
    if (c >= C) return;
    float s = 0.f, ss = 0.f;
    for (int r = r0; r < r0 + 500; ++r) {
        float v = bf2f(t[(size_t)r * C + c]);
        s += v;
        ss += v * v;
    }
    atomicAdd(&sum[c], s);
    atomicAdd(&sumsq[c], ss);
}

__global__ __launch_bounds__(256) void bn_apply(const ushort* __restrict__ t,
                                                const float* __restrict__ sum,
                                                const float* __restrict__ sumsq,
                                                float* __restrict__ h, int C) {
    int c = blockIdx.x * 256 + threadIdx.x;
    int r = blockIdx.y;
    if (c >= C) return;
    float mean = sum[c] * (1.0f / N_NODES);
    float var = sumsq[c] * (1.0f / N_NODES) - mean * mean;
    float rs = rsqrtf(var + 1e-5f);
    h[(size_t)r * C + c] = (bf2f(t[(size_t)r * C + c]) - mean) * rs;
}

// bf16 in -> bf16 out (h feeds bf16-A GEMM / bf16 gather next)
__global__ __launch_bounds__(256) void bn_apply_bb(const ushort* __restrict__ t,
                                                   const float* __restrict__ sum,
                                                   const float* __restrict__ sumsq,
                                                   ushort* __restrict__ h, int C) {
    int c = blockIdx.x * 256 + threadIdx.x;
    int r = blockIdx.y;
    if (c >= C) return;
    float mean = sum[c] * (1.0f / N_NODES);
    float var = sumsq[c] * (1.0f / N_NODES) - mean * mean;
    float rs = rsqrtf(var + 1e-5f);
    h[(size_t)r * C + c] = f2bf((bf2f(t[(size_t)r * C + c]) - mean) * rs);
}

// ---------------------------------------------------------------- BatchNorm (fp32 t, in-place capable)
__global__ __launch_bounds__(256) void col_stats_f(const float* __restrict__ t,
                                                   float* __restrict__ sum,
                                                   float* __restrict__ sumsq, int C) {
    int c = blockIdx.x * 256 + threadIdx.x;
    int r0 = blockIdx.y * 500;
    if (c >= C) return;
    float s = 0.f, ss = 0.f;
    for (int r = r0; r < r0 + 500; ++r) {
        float v = t[(size_t)r * C + c];
        s += v;
        ss += v * v;
    }
    atomicAdd(&sum[c], s);
    atomicAdd(&sumsq[c], ss);
}

__global__ __launch_bounds__(256) void bn_apply_f(const float* __restrict__ t,
                                                  const float* __restrict__ sum,
                                                  const float* __restrict__ sumsq,
                                                  float* __restrict__ h, int C) {
    int c = blockIdx.x * 256 + threadIdx.x;
    int r = blockIdx.y;
    if (c >= C) return;
    float mean = sum[c] * (1.0f / N_NODES);
    float var = sumsq[c] * (1.0f / N_NODES) - mean * mean;
    float rs = rsqrtf(var + 1e-5f);
    h[(size_t)r * C + c] = (t[(size_t)r * C + c] - mean) * rs;
}

// ---------------------------------------------------------------- attention head
__global__ __launch_bounds__(256) void mlp_u(const float* __restrict__ h1,
                                             const float* __restrict__ h2,
                                             const float* __restrict__ h3,
                                             const float* __restrict__ h4,
                                             const float* __restrict__ W,
                                             const float* __restrict__ b,
                                             float* __restrict__ u) {
    int lane = threadIdx.x & 63;
    int wv = threadIdx.x >> 6;
    int row = blockIdx.x * 4 + wv;
    if (row >= N_NODES) return;
    float acc[5] = {0.f, 0.f, 0.f, 0.f, 0.f};
    const float* hs[4] = {h1, h2, h3, h4};
    const int Cs[4] = {500, 500, 2000, 10};
    const int Woff[4] = {0, 500, 1000, 3000};
    for (int sg = 0; sg < 4; ++sg) {
        const float* hp = hs[sg] + (size_t)row * Cs[sg];
        const float* wp = W + (size_t)Woff[sg] * 5;
        for (int k = lane; k < Cs[sg]; k += 64) {
            float a = hp[k];
#pragma unroll
            for (int j = 0; j < 5; ++j) acc[j] += a * wp[k * 5 + j];
        }
    }
#pragma unroll
    for (int j = 0; j < 5; ++j)
        for (int off = 32; off > 0; off >>= 1) acc[j] += __shfl_down(acc[j], off, 64);
    if (lane == 0) {
        float t[5], m = -1e30f;
#pragma unroll
        for (int j = 0; j < 5; ++j) {
            t[j] = tanhf(acc[j] + b[j]);
            m = fmaxf(m, t[j]);
        }
        float s = 0.f;
#pragma unroll
        for (int j = 0; j < 5; ++j) {
            t[j] = expf(t[j] - m);
            s += t[j];
        }
        float inv = 1.0f / s;
        float n2 = 0.f;
#pragma unroll
        for (int j = 0; j < 5; ++j) {
            t[j] *= inv;
            n2 += t[j] * t[j];
        }
        float nrm = fmaxf(sqrtf(n2), 1e-12f);
        float innrm = 1.0f / nrm;
#pragma unroll
        for (int j = 0; j < 5; ++j) u[(size_t)row * 5 + j] = t[j] * innrm;
    }
}

__global__ __launch_bounds__(256) void zout_kernel(const float* __restrict__ h1,
                                                   const float* __restrict__ h2,
                                                   const float* __restrict__ h3,
                                                   const float* __restrict__ h4,
                                                   const float* __restrict__ u,
                                                   float* __restrict__ out) {
    int c = blockIdx.x * 256 + threadIdx.x;
    int row = blockIdx.y;
    if (c >= 3010) return;
    int seg, cl;
    const float* hp;
    if (c < 500)       { seg = 0; cl = c;        hp = h1 + (size_t)row * 500; }
    else if (c < 1000) { seg = 1; cl = c - 500;  hp = h2 + (size_t)row * 500; }
    else if (c < 3000) { seg = 2; cl = c - 1000; hp = h3 + (size_t)row * 2000; }
    else               { seg = 3; cl = c - 3000; hp = h4 + (size_t)row * 10; }
    out[(size_t)row * 3010 + c] = u[(size_t)row * 5 + seg] * hp[cl];
}

// ---------------------------------------------------------------- launch
extern "C" void kernel_launch(void* const* d_in, const int* in_sizes, int n_in,
                              void* d_out, int out_size, void* d_ws, size_t ws_size,
                              hipStream_t stream) {
    const float* x = (const float*)d_in[0];
    const int* adj_rows  = (const int*)d_in[1];
    const int* adj_cols  = (const int*)d_in[2];
    const float* adj_vals = (const float*)d_in[3];
    const int* fadj_rows = (const int*)d_in[4];
    const int* fadj_cols = (const int*)d_in[5];
    const float* fadj_vals = (const float*)d_in[6];
    const int* f1_rows = (const int*)d_in[7];
    const int* f1_cols = (const int*)d_in[8];
    const float* f1_vals = (const float*)d_in[9];
    const int* f2_rows = (const int*)d_in[10];
    const int* f2_cols = (const int*)d_in[11];
    const float* f2_vals = (const float*)d_in[12];
    const float* feaW[4]  = {(const float*)d_in[13], (const float*)d_in[14],
                             (const float*)d_in[15], (const float*)d_in[16]};
    const float* topoW[4] = {(const float*)d_in[17], (const float*)d_in[18],
                             (const float*)d_in[19], (const float*)d_in[20]};
    const float* We1 = (const float*)d_in[21]; const float* be1 = (const float*)d_in[22];
    const float* We2 = (const float*)d_in[23]; const float* be2 = (const float*)d_in[24];
    const float* We3 = (const float*)d_in[25]; const float* be3 = (const float*)d_in[26];
    const float* Wz1 = (const float*)d_in[27]; const float* bz1 = (const float*)d_in[28];
    const float* Wz2 = (const float*)d_in[29]; const float* bz2 = (const float*)d_in[30];
    const float* Wd0 = (const float*)d_in[31]; const float* bd0 = (const float*)d_in[32];
    const float* Wd1 = (const float*)d_in[33]; const float* bd1 = (const float*)d_in[34];
    const float* Wd2 = (const float*)d_in[35]; const float* bd2 = (const float*)d_in[36];
    const float* Wd3 = (const float*)d_in[37]; const float* bd3 = (const float*)d_in[38];
    const float* Wxb = (const float*)d_in[39]; const float* bxb = (const float*)d_in[40];
    const float* mlpW = (const float*)d_in[41]; const float* mlpb = (const float*)d_in[42];

    float* out = (float*)d_out;
    float* out_xbar = out;                    // [20000,1000]
    float* out_z = out + 20000000;            // [20000,10]
    float* out_fea4 = out + 20200000;
    float* out_topo4 = out + 20400000;
    float* out_feadiff4 = out + 20600000;
    float* out_topodiff4 = out + 20800000;
    float* out_zout = out + 21000000;         // [20000,3010]

    char* w = (char*)d_ws;
    auto alloc = [&](size_t bytes) -> char* {
        char* p = w;
        w += (bytes + 255) & ~(size_t)255;
        return p;
    };
    ushort* bufB = (ushort*)alloc((size_t)N_NODES * 2000 * 2);  // sup (bf16, br 1-3)
    ushort* bufC = (ushort*)alloc((size_t)N_NODES * 2000 * 2);  // t   (bf16, br 1-3)
    float* feah1 = (float*)alloc((size_t)N_NODES * 500 * 4);
    float* feah2 = (float*)alloc((size_t)N_NODES * 500 * 4);
    float* feah3 = (float*)alloc((size_t)N_NODES * 2000 * 4);   // aliased as AE bufF
    float* bufF  = feah3;  // AE h3 / d1 scratch; consumed before fea branch writes feah3
    float* bufH  = (float*)alloc((size_t)N_NODES * 2000 * 4);   // fp32 sup/agg scratch
    // bf16 h for branches 1-3 lives in the upper part of bufH's allocation:
    // bufH use never exceeds 20000*500*4 = 40 MB (sup/agg at C<=500, C=10 sup);
    // bufHb occupies bytes [40MB, 120MB) of the 160 MB bufH block.
    ushort* bufHb = (ushort*)(bufH + 10000000);
    float* z1buf = (float*)alloc((size_t)N_NODES * 10 * 4);
    float* dsmall = (float*)alloc((size_t)N_NODES * 10 * 4);
    float* ubuf  = (float*)alloc((size_t)N_NODES * 5 * 4);
    float* ssum  = (float*)alloc(2000 * 4);
    float* ssq   = (float*)alloc(2000 * 4);
    int* counts  = (int*)alloc(N_NODES * 4);
    int* fillctr = (int*)alloc(N_NODES * 4);
    int* row_ptr = (int*)alloc((N_NODES + 1) * 4);
    int* cols_s  = (int*)alloc((size_t)N_EDGES * 4);
    float* vals_s = (float*)alloc((size_t)N_EDGES * 4);

    // bf16-transposed weights
    auto kpad = [](int K) { return ((K + 31) / 32) * 32; };
    struct TW { const float* W; int K, Nc, Kp; ushort* Bt; };
    TW tw[16] = {
        {We1, 1000, 500, 1024, nullptr}, {We2, 500, 500, 512, nullptr},
        {We3, 500, 2000, 512, nullptr},  {Wz1, 2000, 10, 2016, nullptr},
        {Wd1, 10, 2000, 32, nullptr},    {Wd2, 2000, 500, 2016, nullptr},
        {Wd3, 500, 500, 512, nullptr},   {Wxb, 500, 1000, 512, nullptr},
        {feaW[0], 1000, 500, 1024, nullptr}, {feaW[1], 500, 500, 512, nullptr},
        {feaW[2], 500, 2000, 512, nullptr},  {feaW[3], 2000, 10, 2016, nullptr},
        {topoW[0], 1000, 500, 1024, nullptr}, {topoW[1], 500, 500, 512, nullptr},
        {topoW[2], 500, 2000, 512, nullptr},  {topoW[3], 2000, 10, 2016, nullptr},
    };
    for (int i = 0; i < 16; ++i) {
        tw[i].Kp = kpad(tw[i].K);
        tw[i].Bt = (ushort*)alloc((size_t)tw[i].Nc * tw[i].Kp * 2);
        int tot = tw[i].Nc * tw[i].Kp;
        transpose_w<<<(tot + 255) / 256, 256, 0, stream>>>(
            tw[i].W, tw[i].Bt, tw[i].K, tw[i].Nc, tw[i].Kp);
    }

    auto gemm_f = [&](const float* A, const TW& t, const float* bias, float* C,
                      int act, int split) {
        dim3 g((t.Nc + 127) / 128, (N_NODES + 127) / 128);
        mfma_gemm<<<g, 256, 0, stream>>>(A, nullptr, t.Bt, bias, C, nullptr, N_NODES,
                                         t.K, t.Nc, t.Kp, act, split);
    };
    auto gemm_b = [&](const float* A, const TW& t, ushort* C, int act) {
        dim3 g((t.Nc + 127) / 128, (N_NODES + 127) / 128);
        mfma_gemm<<<g, 256, 0, stream>>>(A, nullptr, t.Bt, nullptr, nullptr, C,
                                         N_NODES, t.K, t.Nc, t.Kp, act, 0);
    };
    auto gemm_b16 = [&](const ushort* Ab, const TW& t, ushort* C, int act) {
        dim3 g((t.Nc + 127) / 128, (N_NODES + 127) / 128);
        mfma_gemm<<<g, 256, 0, stream>>>(nullptr, Ab, t.Bt, nullptr, nullptr, C,
                                         N_NODES, t.K, t.Nc, t.Kp, act, 0);
    };

    // ---------------- AE branch ----------------
    gemm_f(x, tw[0], be1, feah1, 1, 0);       // h1
    gemm_f(feah1, tw[1], be2, feah2, 1, 0);   // h2
    gemm_f(feah2, tw[2], be3, bufF, 1, 0);    // h3
    gemm_f(bufF, tw[3], bz1, z1buf, 0, 0);    // z1
    gemm_small<<<(N_NODES + 7) / 8, 256, 0, stream>>>(z1buf, Wz2, bz2, out_z,
                                                      N_NODES, 10, 10, 0);  // z
    gemm_small<<<(N_NODES + 7) / 8, 256, 0, stream>>>(out_z, Wd0, bd0, dsmall,
                                                      N_NODES, 10, 10, 1);  // d0
    gemm_f(dsmall, tw[4], bd1, bufF, 1, 0);   // d1
    gemm_f(bufF, tw[5], bd2, feah1, 1, 0);    // d2 (feah1 scratch)
    gemm_f(feah1, tw[6], bd3, feah2, 1, 0);   // d3 (feah2 scratch)
    gemm_f(feah2, tw[7], bxb, out_xbar, 0, 0);  // x_bar

    // ---------------- GNN branches ----------------
    // Layer plan (A = sparse adj, W = dense weight):
    //  L0 (1000->500): GEMM-first (gather over 500)
    //  L1 (500->500) : GEMM-first
    //  L2 (500->2000): SPMM-FIRST — A@(h@W) == (A@h)@W, gather over 500 not 2000
    //  L3 (2000->10) : GEMM-first (gather over 10)
    struct Br {
        const int* rows; const int* cols; const float* vals;
        int w0;          // index into tw[] of this branch's W1
        int precise;     // 1 = fp32 path + split-A GEMM (fea branch)
        float* final_dest;
    };
    Br brs[4] = {
        {fadj_rows, fadj_cols, fadj_vals, 8, 1, out_fea4},
        {adj_rows, adj_cols, adj_vals, 12, 0, out_topo4},
        {f2_rows, f2_cols, f2_vals, 8, 0, out_feadiff4},
        {f1_rows, f1_cols, f1_vals, 12, 0, out_topodiff4},
    };

    auto bn_zero = [&](int C) {
        zero_i32<<<(C + 255) / 256, 256, 0, stream>>>((int*)ssum, C);
        zero_i32<<<(C + 255) / 256, 256, 0, stream>>>((int*)ssq, C);
    };
    auto bn_f = [&](float* t, int C) {  // fp32 in-place
        bn_zero(C);
        col_stats_f<<<dim3((C + 255) / 256, 40), 256, 0, stream>>>(t, ssum, ssq, C);
        bn_apply_f<<<dim3((C + 255) / 256, N_NODES), 256, 0, stream>>>(t, ssum, ssq,
                                                                       t, C);
    };
    auto bn_bb = [&](const ushort* t, ushort* h, int C) {  // bf16 -> bf16
        bn_zero(C);
        col_stats<<<dim3((C + 255) / 256, 40), 256, 0, stream>>>(t, ssum, ssq, C);
        bn_apply_bb<<<dim3((C + 255) / 256, N_NODES), 256, 0, stream>>>(t, ssum, ssq,
                                                                        h, C);
    };
    auto bn_bf = [&](const ushort* t, float* h, int C) {  // bf16 -> fp32 (final)
        bn_zero(C);
        col_stats<<<dim3((C + 255) / 256, 40), 256, 0, stream>>>(t, ssum, ssq, C);
        bn_apply<<<dim3((C + 255) / 256, N_NODES), 256, 0, stream>>>(t, ssum, ssq,
                                                                     h, C);
    };
    auto spmmA_f = [&](const float* sup, float* dst, int C) {
        spmm_act_f<<<dim3(N_NODES, (C + 255) / 256), 256, 0, stream>>>(
            sup, row_ptr, cols_s, vals_s, dst, C);
    };
    auto spmmA_bf = [&](const ushort* sup, ushort* dst, int C) {
        spmm_act_bf<<<dim3(N_NODES, (C + 511) / 512), 256, 0, stream>>>(
            sup, row_ptr, cols_s, vals_s, dst, C);
    };

    for (int b = 0; b < 4; ++b) {
        // CSR build
        zero_i32<<<(N_NODES + 255) / 256, 256, 0, stream>>>(counts, N_NODES);
        hist_kernel<<<(N_EDGES + 255) / 256, 256, 0, stream>>>(brs[b].rows, counts);
        scan_kernel<<<1, 1024, 0, stream>>>(counts, row_ptr);
        zero_i32<<<(N_NODES + 255) / 256, 256, 0, stream>>>(fillctr, N_NODES);
        fill_kernel<<<(N_EDGES + 255) / 256, 256, 0, stream>>>(
            brs[b].rows, brs[b].cols, brs[b].vals, row_ptr, fillctr, cols_s, vals_s);

        int w0 = brs[b].w0;
        if (brs[b].precise) {
            // ---- fea branch: fp32 sup/agg, split-A GEMMs ----
            // L0
            gemm_f(x, tw[w0], nullptr, bufH, 0, 1);
            spmmA_f(bufH, feah1, 500);
            bn_f(feah1, 500);
            // L1
            gemm_f(feah1, tw[w0 + 1], nullptr, bufH, 0, 1);
            spmmA_f(bufH, feah2, 500);
            bn_f(feah2, 500);
            // L2: spmm-first (gather fp32 h over 500, then GEMM w/ fused leaky+elu)
            spmm_gather_f<<<dim3(N_NODES, 2), 256, 0, stream>>>(
                feah2, row_ptr, cols_s, vals_s, bufH, 500);
            gemm_f(bufH, tw[w0 + 2], nullptr, feah3, 2, 1);
            bn_f(feah3, 2000);
            // L3
            gemm_f(feah3, tw[w0 + 3], nullptr, bufH, 0, 1);
            spmmA_f(bufH, brs[b].final_dest, 10);
            bn_f(brs[b].final_dest, 10);
        } else {
            // ---- bf16 branches ----
            // L0
            gemm_b(x, tw[w0], bufB, 0);
            spmmA_bf(bufB, bufC, 500);
            bn_bb(bufC, bufHb, 500);
            // L1
            gemm_b16(bufHb, tw[w0 + 1], bufB, 0);
            spmmA_bf(bufB, bufC, 500);
            bn_bb(bufC, bufHb, 500);
            // L2: spmm-first (gather bf16 h over 500 -> fp32 agg -> GEMM act=2)
            spmm_gather_bf<<<dim3(N_NODES, 1), 256, 0, stream>>>(
                bufHb, row_ptr, cols_s, vals_s, bufH, 500);
            gemm_b(bufH, tw[w0 + 2], bufC, 2);
            bn_bb(bufC, bufHb, 2000);
            // L3
            gemm_b16(bufHb, tw[w0 + 3], bufB, 0);
            spmmA_bf(bufB, bufC, 10);
            bn_bf(bufC, brs[b].final_dest, 10);
        }
    }

    // ---------------- attention fusion head ----------------
    mlp_u<<<(N_NODES + 3) / 4, 256, 0, stream>>>(feah1, feah2, feah3, out_fea4,
                                                 mlpW, mlpb, ubuf);
    zout_kernel<<<dim3(12, N_NODES), 256, 0, stream>>>(feah1, feah2, feah3, out_fea4,
                                                       ubuf, out_zout);
}

// Round 2
// 6295.425 us; speedup vs baseline: 1.7166x; 1.4373x over previous
//
#include <hip/hip_runtime.h>
#include <cstdint>
#include <cstddef>

#define N_NODES 20000
#define N_EDGES 640000

typedef short short8 __attribute__((ext_vector_type(8)));
typedef float floatx4 __attribute__((ext_vector_type(4)));

__device__ __forceinline__ ushort f2bf(float f) {
    uint32_t u = __float_as_uint(f);
    uint32_t r = (u + 0x7fff + ((u >> 16) & 1)) >> 16;
    return (ushort)r;
}
__device__ __forceinline__ float bf2f(ushort u) {
    return __uint_as_float(((uint32_t)u) << 16);
}

// ---------------------------------------------------------------- utilities
__global__ __launch_bounds__(256) void zero_i32(int* __restrict__ p, int n) {
    int i = blockIdx.x * 256 + threadIdx.x;
    if (i < n) p[i] = 0;
}

// weight pre-transpose + bf16 convert: W[K][Nc] fp32 -> Bt[Nc][Kp] bf16 (zero pad)
__global__ __launch_bounds__(256) void transpose_w(const float* __restrict__ W,
                                                   ushort* __restrict__ Bt,
                                                   int K, int Nc, int Kp) {
    int idx = blockIdx.x * 256 + threadIdx.x;
    if (idx >= Nc * Kp) return;
    int n = idx / Kp, k = idx % Kp;
    Bt[idx] = (k < K) ? f2bf(W[(size_t)k * Nc + n]) : (ushort)0;
}

// ---------------------------------------------------------------- CSR build
__global__ __launch_bounds__(256) void hist_kernel(const int* __restrict__ rows,
                                                   int* __restrict__ counts) {
    int e = blockIdx.x * 256 + threadIdx.x;
    if (e < N_EDGES) atomicAdd(&counts[rows[e]], 1);
}

__global__ __launch_bounds__(1024) void scan_kernel(const int* __restrict__ counts,
                                                    int* __restrict__ row_ptr) {
    __shared__ int part[1024];
    const int CH = 20;
    int tid = threadIdx.x;
    int t0 = tid * CH;
    int s = 0;
    for (int i = 0; i < CH; ++i) {
        int p = t0 + i;
        if (p < N_NODES) s += counts[p];
    }
    part[tid] = s;
    __syncthreads();
    for (int off = 1; off < 1024; off <<= 1) {
        int v = (tid >= off) ? part[tid - off] : 0;
        __syncthreads();
        if (tid >= off) part[tid] += v;
        __syncthreads();
    }
    int base = (tid == 0) ? 0 : part[tid - 1];
    for (int i = 0; i < CH; ++i) {
        int p = t0 + i;
        if (p < N_NODES) {
            row_ptr[p] = base;
            base += counts[p];
            if (p == N_NODES - 1) row_ptr[N_NODES] = base;
        }
    }
}

__global__ __launch_bounds__(256) void fill_kernel(const int* __restrict__ rows,
                                                   const int* __restrict__ cols,
                                                   const float* __restrict__ vals,
                                                   const int* __restrict__ row_ptr,
                                                   int* __restrict__ fillctr,
                                                   int* __restrict__ cols_s,
                                                   float* __restrict__ vals_s) {
    int e = blockIdx.x * 256 + threadIdx.x;
    if (e < N_EDGES) {
        int r = rows[e];
        int pos = atomicAdd(&fillctr[r], 1);
        int idx = row_ptr[r] + pos;
        cols_s[idx] = cols[e];
        vals_s[idx] = vals[e];
    }
}

// ---------------------------------------------------------------- MFMA GEMM
// C[M,Nc] = act(A[M,K] @ B[K,Nc] + bias).
// AMODE: 0 = fp32 A; 1 = fp32 A with hi/lo bf16 split (~fp32 accuracy);
//        2 = bf16 A (row stride lda, pad region handled by K-guard).
// B pre-transposed bf16 [Nc][Kp]. Output: Cb!=null -> bf16 else fp32 (stride ldc).
// act: 1=relu, 2=leaky(0.2)+elu.
// Grid is 1-D, XCD-group swizzled: all col-tiles of one row-panel share
// (id mod 8) -> same XCD -> A row-panel fetched into that XCD's L2 once.
// Pipeline: register double-buffer prefetch: loads for kt+1 issued before
// MFMA(kt) so global latency hides under compute + barriers.
template <int AMODE>
__global__ __launch_bounds__(256) void mfma_gemm(
    const float* __restrict__ A, const ushort* __restrict__ Ab,
    const ushort* __restrict__ Bt,
    const float* __restrict__ bias, float* __restrict__ Cf,
    ushort* __restrict__ Cb, int M, int K, int lda, int Nc, int ldc, int Kp,
    int act, int NX, int NY) {
    __shared__ __align__(16) ushort As[128][40];  // +8 pad breaks bank aliasing
    __shared__ __align__(16) ushort Bs[128][40];
    __shared__ __align__(16) ushort Al[(AMODE == 1) ? 128 : 1][40];  // lo (split)

    // XCD-group swizzle: id = r8 + 8*(bx + NX*q); y = r8 + 8q.
    // All bx for fixed (r8,q) are congruent mod 8 -> same XCD.
    int id = blockIdx.x;
    int r8 = id & 7, tt = id >> 3;
    int bx = tt % NX, qq = tt / NX;
    int by = r8 + 8 * qq;
    if (by >= NY) return;
    int row0 = by * 128, col0 = bx * 128;

    int tid = threadIdx.x;
    int wave = tid >> 6, lane = tid & 63;
    int wr = (wave >> 1) * 64, wc = (wave & 1) * 64;
    int m16 = lane & 15, quad = lane >> 4;

    floatx4 acc[4][4] = {};
    int KT = (K + 31) >> 5;
    bool k4 = (K & 3) == 0;

    // staging addressing
    int arf = tid >> 3, akq = (tid & 7) << 2;  // fp32 A: rows arf+32p, k akq..+3
    int arb = tid >> 2, akb = (tid & 3) << 3;  // bf16 A: rows arb+64p, k akb..+7
    int bn_ = tid >> 2, bch = (tid & 3) << 3;  // B: col bn_+64p, k bch..+7

    // register staging double buffers (only one A-flavor live per instantiation)
    float4 avA[4], avB[4];
    uint4 abvA[2], abvB[2], bvA[2], bvB[2];

#define ISSUE_T(AV, ABV, BV, KTARG)                                          \
    do {                                                                     \
        int k0_ = (KTARG) << 5;                                              \
        if constexpr (AMODE == 2) {                                          \
            for (int p = 0; p < 2; ++p) {                                    \
                int grow = row0 + arb + p * 64;                              \
                int gk = k0_ + akb;                                          \
                uint4 z = {0u, 0u, 0u, 0u};                                  \
                if (grow < M) {                                              \
                    const ushort* ap = Ab + (size_t)grow * lda + gk;         \
                    if (gk + 7 < K) {                                        \
                        z = *(const uint4*)ap;                               \
                    } else {                                                 \
                        ushort tm[8] = {0, 0, 0, 0, 0, 0, 0, 0};             \
                        for (int j = 0; j < 8; ++j)                          \
                            if (gk + j < K) tm[j] = ap[j];                   \
                        z.x = (uint)tm[0] | ((uint)tm[1] << 16);             \
                        z.y = (uint)tm[2] | ((uint)tm[3] << 16);             \
                        z.z = (uint)tm[4] | ((uint)tm[5] << 16);             \
                        z.w = (uint)tm[6] | ((uint)tm[7] << 16);             \
                    }                                                        \
                }                                                            \
                ABV[p] = z;                                                  \
            }                                                                \
        } else {                                                             \
            for (int p = 0; p < 4; ++p) {                                    \
                int grow = row0 + arf + p * 32;                              \
                int gk = k0_ + akq;                                          \
                float4 v = {0.f, 0.f, 0.f, 0.f};                             \
                if (grow < M) {                                              \
                    const float* ap = A + (size_t)grow * lda + gk;           \
                    if (k4 && gk + 3 < K) {                                  \
                        v = *(const float4*)ap;                              \
                    } else {                                                 \
                        if (gk < K) v.x = ap[0];                             \
                        if (gk + 1 < K) v.y = ap[1];                         \
                        if (gk + 2 < K) v.z = ap[2];                         \
                        if (gk + 3 < K) v.w = ap[3];                         \
                    }                                                        \
                }                                                            \
                AV[p] = v;                                                   \
            }                                                                \
        }                                                                    \
        for (int p = 0; p < 2; ++p) {                                        \
            int gcol = col0 + bn_ + p * 64;                                  \
            uint4 z = {0u, 0u, 0u, 0u};                                      \
            if (gcol < Nc) z = *(const uint4*)&Bt[(size_t)gcol * Kp + k0_ + bch]; \
            BV[p] = z;                                                       \
        }                                                                    \
    } while (0)

#define WRITE_T(AV, ABV, BV)                                                 \
    do {                                                                     \
        if constexpr (AMODE == 2) {                                          \
            for (int p = 0; p < 2; ++p)                                      \
                *(uint4*)&As[arb + p * 64][akb] = ABV[p];                    \
        } else {                                                             \
            for (int p = 0; p < 4; ++p) {                                    \
                float4 v = AV[p];                                            \
                ushort4 hi;                                                  \
                hi.x = f2bf(v.x); hi.y = f2bf(v.y);                          \
                hi.z = f2bf(v.z); hi.w = f2bf(v.w);                          \
                *(ushort4*)&As[arf + p * 32][akq] = hi;                      \
                if constexpr (AMODE == 1) {                                  \
                    ushort4 lo;                                              \
                    lo.x = f2bf(v.x - bf2f(hi.x));                           \
                    lo.y = f2bf(v.y - bf2f(hi.y));                           \
                    lo.z = f2bf(v.z - bf2f(hi.z));                           \
                    lo.w = f2bf(v.w - bf2f(hi.w));                           \
                    *(ushort4*)&Al[arf + p * 32][akq] = lo;                  \
                }                                                            \
            }                                                                \
        }                                                                    \
        for (int p = 0; p < 2; ++p)                                          \
            *(uint4*)&Bs[bn_ + p * 64][bch] = BV[p];                         \
    } while (0)

    ISSUE_T(avA, abvA, bvA, 0);
    for (int kt = 0; kt < KT; ++kt) {
        if (kt) __syncthreads();  // prior MFMA phase done reading LDS
        if ((kt & 1) == 0) {
            WRITE_T(avA, abvA, bvA);
            if (kt + 1 < KT) ISSUE_T(avB, abvB, bvB, kt + 1);
        } else {
            WRITE_T(avB, abvB, bvB);
            if (kt + 1 < KT) ISSUE_T(avA, abvA, bvA, kt + 1);
        }
        __syncthreads();
        // --- MFMA ---
        short8 a[4], b[4];
        int ko = quad * 8;
#pragma unroll
        for (int i = 0; i < 4; ++i) a[i] = *(short8*)&As[wr + i * 16 + m16][ko];
#pragma unroll
        for (int j = 0; j < 4; ++j) b[j] = *(short8*)&Bs[wc + j * 16 + m16][ko];
        if constexpr (AMODE == 1) {
            short8 al[4];
#pragma unroll
            for (int i = 0; i < 4; ++i) al[i] = *(short8*)&Al[wr + i * 16 + m16][ko];
#pragma unroll
            for (int i = 0; i < 4; ++i)
#pragma unroll
                for (int j = 0; j < 4; ++j)
                    acc[i][j] = __builtin_amdgcn_mfma_f32_16x16x32_bf16(
                        al[i], b[j], acc[i][j], 0, 0, 0);
        }
#pragma unroll
        for (int i = 0; i < 4; ++i)
#pragma unroll
            for (int j = 0; j < 4; ++j)
                acc[i][j] = __builtin_amdgcn_mfma_f32_16x16x32_bf16(
                    a[i], b[j], acc[i][j], 0, 0, 0);
    }
#undef ISSUE_T
#undef WRITE_T

    // --- epilogue ---
#pragma unroll
    for (int i = 0; i < 4; ++i) {
        int rbase = row0 + wr + i * 16 + quad * 4;
#pragma unroll
        for (int j = 0; j < 4; ++j) {
            int gcol = col0 + wc + j * 16 + m16;
            if (gcol >= Nc) continue;
            float bv = bias ? bias[gcol] : 0.f;
#pragma unroll
            for (int r = 0; r < 4; ++r) {
                int grow = rbase + r;
                if (grow >= M) continue;
                float v = acc[i][j][r] + bv;
                if (act == 1) v = v > 0.f ? v : 0.f;
                else if (act == 2) v = v > 0.f ? v : (expf(0.2f * v) - 1.0f);
                if (Cb) Cb[(size_t)grow * ldc + gcol] = f2bf(v);
                else Cf[(size_t)grow * ldc + gcol] = v;
            }
        }
    }
}

// ---------------------------------------------------------------- small vector GEMM
__global__ __launch_bounds__(256) void gemm_small(
    const float* __restrict__ A, const float* __restrict__ B,
    const float* __restrict__ bias, float* __restrict__ C,
    int M, int K, int Nc, int act) {
    int row = blockIdx.x * 8 + (threadIdx.x >> 5);
    int c = threadIdx.x & 31;
    if (row >= M || c >= Nc) return;
    float acc = bias ? bias[c] : 0.f;
    for (int k = 0; k < K; ++k) acc += A[(size_t)row * K + k] * B[(size_t)k * Nc + c];
    if (act) acc = acc > 0.f ? acc : 0.f;
    C[(size_t)row * Nc + c] = acc;
}

// ---------------------------------------------------------------- SpMM + act (bf16)
__global__ __launch_bounds__(256) void spmm_act_bf(const ushort* __restrict__ sup,
                                                   const int* __restrict__ row_ptr,
                                                   const int* __restrict__ cols_s,
                                                   const float* __restrict__ vals_s,
                                                   ushort* __restrict__ t, int C) {
    int r = blockIdx.x;
    int f0 = blockIdx.y * 512 + threadIdx.x * 2;
    int s = row_ptr[r], e = row_ptr[r + 1];
    float a0 = 0.f, a1 = 0.f;
    if (f0 < C) {
        for (int i = s; i < e; ++i) {
            float v = vals_s[i];
            int c = cols_s[i];
            uint u = *(const uint*)&sup[(size_t)c * C + f0];
            a0 += v * bf2f((ushort)(u & 0xffff));
            a1 += v * bf2f((ushort)(u >> 16));
        }
        float r0 = a0 > 0.f ? a0 : (expf(0.2f * a0) - 1.f);
        float r1 = a1 > 0.f ? a1 : (expf(0.2f * a1) - 1.f);
        ushort2 w;
        w.x = f2bf(r0);
        w.y = f2bf(r1);
        *(ushort2*)&t[(size_t)r * C + f0] = w;
    }
}

// SpMM + act, fp32 sup in -> bf16 t out (f2 branch reusing fea's precise L0 sup)
__global__ __launch_bounds__(256) void spmm_act_fb(const float* __restrict__ sup,
                                                   const int* __restrict__ row_ptr,
                                                   const int* __restrict__ cols_s,
                                                   const float* __restrict__ vals_s,
                                                   ushort* __restrict__ t, int C) {
    int r = blockIdx.x;
    int f0 = blockIdx.y * 512 + threadIdx.x * 2;
    if (f0 >= C) return;
    int s = row_ptr[r], e = row_ptr[r + 1];
    float a0 = 0.f, a1 = 0.f;
    for (int i = s; i < e; ++i) {
        float v = vals_s[i];
        int c = cols_s[i];
        float2 u = *(const float2*)&sup[(size_t)c * C + f0];
        a0 += v * u.x;
        a1 += v * u.y;
    }
    float r0 = a0 > 0.f ? a0 : (expf(0.2f * a0) - 1.f);
    float r1 = a1 > 0.f ? a1 : (expf(0.2f * a1) - 1.f);
    ushort2 w;
    w.x = f2bf(r0);
    w.y = f2bf(r1);
    *(ushort2*)&t[(size_t)r * C + f0] = w;
}

// SpMM gather only (bf16 in stride hld, fp32 out): A@(h@W) == (A@h)@W
__global__ __launch_bounds__(256) void spmm_gather_bf(const ushort* __restrict__ h,
                                                      const int* __restrict__ row_ptr,
                                                      const int* __restrict__ cols_s,
                                                      const float* __restrict__ vals_s,
                                                      float* __restrict__ agg, int C,
                                                      int hld) {
    int r = blockIdx.x;
    int f0 = blockIdx.y * 512 + threadIdx.x * 2;
    if (f0 >= C) return;
    int s = row_ptr[r], e = row_ptr[r + 1];
    float a0 = 0.f, a1 = 0.f;
    for (int i = s; i < e; ++i) {
        float v = vals_s[i];
        int c = cols_s[i];
        uint u = *(const uint*)&h[(size_t)c * hld + f0];
        a0 += v * bf2f((ushort)(u & 0xffff));
        a1 += v * bf2f((ushort)(u >> 16));
    }
    float2 w;
    w.x = a0;
    w.y = a1;
    *(float2*)&agg[(size_t)r * C + f0] = w;
}

// ---------------------------------------------------------------- SpMM + act (fp32)
__global__ __launch_bounds__(256) void spmm_act_f(const float* __restrict__ sup,
                                                  const int* __restrict__ row_ptr,
                                                  const int* __restrict__ cols_s,
                                                  const float* __restrict__ vals_s,
                                                  float* __restrict__ t, int C) {
    int r = blockIdx.x;
    int f = blockIdx.y * 256 + threadIdx.x;
    int s = row_ptr[r], e = row_ptr[r + 1];
    float acc = 0.f;
    for (int i = s; i < e; ++i) {
        float v = vals_s[i];
        int c = cols_s[i];
        if (f < C) acc += v * sup[(size_t)c * C + f];
    }
    if (f < C) {
        float a = acc;
        t[(size_t)r * C + f] = a > 0.f ? a : (expf(0.2f * a) - 1.0f);
    }
}

// ---------------------------------------------------------------- SpMM gather only (fp32)
__global__ __launch_bounds__(256) void spmm_gather_f(const float* __restrict__ h,
                                                     const int* __restrict__ row_ptr,
                                                     const int* __restrict__ cols_s,
                                                     const float* __restrict__ vals_s,
                                                     float* __restrict__ agg, int C) {
    int r = blockIdx.x;
    int f = blockIdx.y * 256 + threadIdx.x;
    int s = row_ptr[r], e = row_ptr[r + 1];
    float acc = 0.f;
    for (int i = s; i < e; ++i) {
        float v = vals_s[i];
        int c = cols_s[i];
        if (f < C) acc += v * h[(size_t)c * C + f];
    }
    if (f < C) agg[(size_t)r * C + f] = acc;
}

// ---------------------------------------------------------------- BatchNorm (bf16 t)
__global__ __launch_bounds__(256) void col_stats(const ushort* __restrict__ t,
                                                 float* __restrict__ sum,
                                                 float* __restrict__ sumsq, int C) {
    int c = blockIdx.x * 256 + threadIdx.x;
    int r0 = blockIdx.y * 500;
    if (c >= C) return;
    float s = 0.f, ss = 0.f;
    for (int r = r0; r < r0 + 500; ++r) {
        float v = bf2f(t[(size_t)r * C + c]);
        s += v;
        ss += v * v;
    }
    atomicAdd(&sum[c], s);
    atomicAdd(&sumsq[c], ss);
}

__global__ __launch_bounds__(256) void bn_apply(const ushort* __restrict__ t,
                                                const float* __restrict__ sum,
                                                const float* __restrict__ sumsq,
                                                float* __restrict__ h, int C) {
    int c = blockIdx.x * 256 + threadIdx.x;
    int r = blockIdx.y;
    if (c >= C) return;
    float mean = sum[c] * (1.0f / N_NODES);
    float var = sumsq[c] * (1.0f / N_NODES) - mean * mean;
    float rs = rsqrtf(var + 1e-5f);
    h[(size_t)r * C + c] = (bf2f(t[(size_t)r * C + c]) - mean) * rs;
}

// bf16 in -> bf16 out (stride ldh; pad region left garbage, GEMM K-guards it)
__global__ __launch_bounds__(256) void bn_apply_bb(const ushort* __restrict__ t,
                                                   const float* __restrict__ sum,
                                                   const float* __restrict__ sumsq,
                                                   ushort* __restrict__ h, int C,
                                                   int ldh) {
    int c = blockIdx.x * 256 + threadIdx.x;
    int r = blockIdx.y;
    if (c >= C) return;
    float mean = sum[c] * (1.0f / N_NODES);
    float var = sumsq[c] * (1.0f / N_NODES) - mean * mean;
    float rs = rsqrtf(var + 1e-5f);
    h[(size_t)r * ldh + c] = f2bf((bf2f(t[(size_t)r * C + c]) - mean) * rs);
}

// ---------------------------------------------------------------- BatchNorm (fp32)
__global__ __launch_bounds__(256) void col_stats_f(const float* __restrict__ t,
                                                   float* __restrict__ sum,
                                                   float* __restrict__ sumsq, int C) {
    int c = blockIdx.x * 256 + threadIdx.x;
    int r0 = blockIdx.y * 500;
    if (c >= C) return;
    float s = 0.f, ss = 0.f;
    for (int r = r0; r < r0 + 500; ++r) {
        float v = t[(size_t)r * C + c];
        s += v;
        ss += v * v;
    }
    atomicAdd(&sum[c], s);
    atomicAdd(&sumsq[c], ss);
}

__global__ __launch_bounds__(256) void bn_apply_f(const float* __restrict__ t,
                                                  const float* __restrict__ sum,
                                                  const float* __restrict__ sumsq,
                                                  float* __restrict__ h, int C) {
    int c = blockIdx.x * 256 + threadIdx.x;
    int r = blockIdx.y;
    if (c >= C) return;
    float mean = sum[c] * (1.0f / N_NODES);
    float var = sumsq[c] * (1.0f / N_NODES) - mean * mean;
    float rs = rsqrtf(var + 1e-5f);
    h[(size_t)r * C + c] = (t[(size_t)r * C + c] - mean) * rs;
}

// ---------------------------------------------------------------- attention head
__global__ __launch_bounds__(256) void mlp_u(const float* __restrict__ h1,
                                             const float* __restrict__ h2,
                                             const float* __restrict__ h3,
                                             const float* __restrict__ h4,
                                             const float* __restrict__ W,
                                             const float* __restrict__ b,
                                             float* __restrict__ u) {
    int lane = threadIdx.x & 63;
    int wv = threadIdx.x >> 6;
    int row = blockIdx.x * 4 + wv;
    if (row >= N_NODES) return;
    float acc[5] = {0.f, 0.f, 0.f, 0.f, 0.f};
    const float* hs[4] = {h1, h2, h3, h4};
    const int Cs[4] = {500, 500, 2000, 10};
    const int Woff[4] = {0, 500, 1000, 3000};
    for (int sg = 0; sg < 4; ++sg) {
        const float* hp = hs[sg] + (size_t)row * Cs[sg];
        const float* wp = W + (size_t)Woff[sg] * 5;
        for (int k = lane; k < Cs[sg]; k += 64) {
            float a = hp[k];
#pragma unroll
            for (int j = 0; j < 5; ++j) acc[j] += a * wp[k * 5 + j];
        }
    }
#pragma unroll
    for (int j = 0; j < 5; ++j)
        for (int off = 32; off > 0; off >>= 1) acc[j] += __shfl_down(acc[j], off, 64);
    if (lane == 0) {
        float t[5], m = -1e30f;
#pragma unroll
        for (int j = 0; j < 5; ++j) {
            t[j] = tanhf(acc[j] + b[j]);
            m = fmaxf(m, t[j]);
        }
        float s = 0.f;
#pragma unroll
        for (int j = 0; j < 5; ++j) {
            t[j] = expf(t[j] - m);
            s += t[j];
        }
        float inv = 1.0f / s;
        float n2 = 0.f;
#pragma unroll
        for (int j = 0; j < 5; ++j) {
            t[j] *= inv;
            n2 += t[j] * t[j];
        }
        float nrm = fmaxf(sqrtf(n2), 1e-12f);
        float innrm = 1.0f / nrm;
#pragma unroll
        for (int j = 0; j < 5; ++j) u[(size_t)row * 5 + j] = t[j] * innrm;
    }
}

__global__ __launch_bounds__(256) void zout_kernel(const float* __restrict__ h1,
                                                   const float* __restrict__ h2,
                                                   const float* __restrict__ h3,
                                                   const float* __restrict__ h4,
                                                   const float* __restrict__ u,
                                                   float* __restrict__ out) {
    int c = blockIdx.x * 256 + threadIdx.x;
    int row = blockIdx.y;
    if (c >= 3010) return;
    int seg, cl;
    const float* hp;
    if (c < 500)       { seg = 0; cl = c;        hp = h1 + (size_t)row * 500; }
    else if (c < 1000) { seg = 1; cl = c - 500;  hp = h2 + (size_t)row * 500; }
    else if (c < 3000) { seg = 2; cl = c - 1000; hp = h3 + (size_t)row * 2000; }
    else               { seg = 3; cl = c - 3000; hp = h4 + (size_t)row * 10; }
    out[(size_t)row * 3010 + c] = u[(size_t)row * 5 + seg] * hp[cl];
}

// ---------------------------------------------------------------- launch
extern "C" void kernel_launch(void* const* d_in, const int* in_sizes, int n_in,
                              void* d_out, int out_size, void* d_ws, size_t ws_size,
                              hipStream_t stream) {
    const float* x = (const float*)d_in[0];
    const int* adj_rows  = (const int*)d_in[1];
    const int* adj_cols  = (const int*)d_in[2];
    const float* adj_vals = (const float*)d_in[3];
    const int* fadj_rows = (const int*)d_in[4];
    const int* fadj_cols = (const int*)d_in[5];
    const float* fadj_vals = (const float*)d_in[6];
    const int* f1_rows = (const int*)d_in[7];
    const int* f1_cols = (const int*)d_in[8];
    const float* f1_vals = (const float*)d_in[9];
    const int* f2_rows = (const int*)d_in[10];
    const int* f2_cols = (const int*)d_in[11];
    const float* f2_vals = (const float*)d_in[12];
    const float* feaW[4]  = {(const float*)d_in[13], (const float*)d_in[14],
                             (const float*)d_in[15], (const float*)d_in[16]};
    const float* topoW[4] = {(const float*)d_in[17], (const float*)d_in[18],
                             (const float*)d_in[19], (const float*)d_in[20]};
    const float* We1 = (const float*)d_in[21]; const float* be1 = (const float*)d_in[22];
    const float* We2 = (const float*)d_in[23]; const float* be2 = (const float*)d_in[24];
    const float* We3 = (const float*)d_in[25]; const float* be3 = (const float*)d_in[26];
    const float* Wz1 = (const float*)d_in[27]; const float* bz1 = (const float*)d_in[28];
    const float* Wz2 = (const float*)d_in[29]; const float* bz2 = (const float*)d_in[30];
    const float* Wd0 = (const float*)d_in[31]; const float* bd0 = (const float*)d_in[32];
    const float* Wd1 = (const float*)d_in[33]; const float* bd1 = (const float*)d_in[34];
    const float* Wd2 = (const float*)d_in[35]; const float* bd2 = (const float*)d_in[36];
    const float* Wd3 = (const float*)d_in[37]; const float* bd3 = (const float*)d_in[38];
    const float* Wxb = (const float*)d_in[39]; const float* bxb = (const float*)d_in[40];
    const float* mlpW = (const float*)d_in[41]; const float* mlpb = (const float*)d_in[42];

    float* out = (float*)d_out;
    float* out_xbar = out;                    // [20000,1000]
    float* out_z = out + 20000000;            // [20000,10]
    float* out_fea4 = out + 20200000;
    float* out_topo4 = out + 20400000;
    float* out_feadiff4 = out + 20600000;
    float* out_topodiff4 = out + 20800000;
    float* out_zout = out + 21000000;         // [20000,3010]

    char* w = (char*)d_ws;
    auto alloc = [&](size_t bytes) -> char* {
        char* p = w;
        w += (bytes + 255) & ~(size_t)255;
        return p;
    };
    ushort* bufB = (ushort*)alloc((size_t)N_NODES * 2000 * 2);  // sup / AE h3,d1 (bf16)
    ushort* bufC = (ushort*)alloc((size_t)N_NODES * 2000 * 2);  // t / AE h1,h2,d2,d3
    float* feah1 = (float*)alloc((size_t)N_NODES * 500 * 4);
    float* feah2 = (float*)alloc((size_t)N_NODES * 500 * 4);
    float* feah3 = (float*)alloc((size_t)N_NODES * 2000 * 4);
    float* bufH  = (float*)alloc((size_t)N_NODES * 2000 * 4);   // 160 MB, partitioned:
    // [0,40MB): fp32 sup/agg scratch (C<=500)
    // [40,120MB): bufHb — bf16 h for branches 1-3 (stride 512 @C=500, 2000 @C=2000)
    // [120,160MB): supFea — fea/f2 shared fp32 L0 support (20000x500)
    ushort* bufHb = (ushort*)(bufH + 10000000);
    float* supFea = bufH + 30000000;
    float* z1buf = (float*)alloc((size_t)N_NODES * 10 * 4);
    float* dsmall = (float*)alloc((size_t)N_NODES * 10 * 4);
    float* ubuf  = (float*)alloc((size_t)N_NODES * 5 * 4);
    float* ssum  = (float*)alloc(2000 * 4);
    float* ssq   = (float*)alloc(2000 * 4);
    int* counts  = (int*)alloc(N_NODES * 4);
    int* fillctr = (int*)alloc(N_NODES * 4);
    int* row_ptr = (int*)alloc((N_NODES + 1) * 4);
    int* cols_s  = (int*)alloc((size_t)N_EDGES * 4);
    float* vals_s = (float*)alloc((size_t)N_EDGES * 4);
    ushort* supTopo = (ushort*)alloc((size_t)N_NODES * 500 * 2);  // shared topo L0 sup

    // AE bf16 intermediates aliased into bufB/bufC (free during AE phase)
    ushort* aeh1b = bufC;                       // 20000x500 @ldc 512
    ushort* aeh2b = bufC + (size_t)N_NODES * 512;
    ushort* aeh3b = bufB;                       // 20000x2000

    // bf16-transposed weights
    auto kpad = [](int K) { return ((K + 31) / 32) * 32; };
    struct TW { const float* W; int K, Nc, Kp; ushort* Bt; };
    TW tw[16] = {
        {We1, 1000, 500, 1024, nullptr}, {We2, 500, 500, 512, nullptr},
        {We3, 500, 2000, 512, nullptr},  {Wz1, 2000, 10, 2016, nullptr},
        {Wd1, 10, 2000, 32, nullptr},    {Wd2, 2000, 500, 2016, nullptr},
        {Wd3, 500, 500, 512, nullptr},   {Wxb, 500, 1000, 512, nullptr},
        {feaW[0], 1000, 500, 1024, nullptr}, {feaW[1], 500, 500, 512, nullptr},
        {feaW[2], 500, 2000, 512, nullptr},  {feaW[3], 2000, 10, 2016, nullptr},
        {topoW[0], 1000, 500, 1024, nullptr}, {topoW[1], 500, 500, 512, nullptr},
        {topoW[2], 500, 2000, 512, nullptr},  {topoW[3], 2000, 10, 2016, nullptr},
    };
    for (int i = 0; i < 16; ++i) {
        tw[i].Kp = kpad(tw[i].K);
        tw[i].Bt = (ushort*)alloc((size_t)tw[i].Nc * tw[i].Kp * 2);
        int tot = tw[i].Nc * tw[i].Kp;
        transpose_w<<<(tot + 255) / 256, 256, 0, stream>>>(
            tw[i].W, tw[i].Bt, tw[i].K, tw[i].Nc, tw[i].Kp);
    }

    const int NYB = (N_NODES + 127) / 128;            // 157
    const int NY8 = 8 * ((NYB + 7) / 8);              // 160 swizzle slots
    auto gemm_f32 = [&](const float* A, const TW& t, const float* bias, float* Cf,
                        ushort* Cb, int lda, int ldc, int act) {
        int NX = (t.Nc + 127) / 128;
        mfma_gemm<0><<<NX * NY8, 256, 0, stream>>>(A, nullptr, t.Bt, bias, Cf, Cb,
                                                   N_NODES, t.K, lda, t.Nc, ldc,
                                                   t.Kp, act, NX, NYB);
    };
    auto gemm_spl = [&](const float* A, const TW& t, float* Cf, int lda, int ldc,
                        int act) {
        int NX = (t.Nc + 127) / 128;
        mfma_gemm<1><<<NX * NY8, 256, 0, stream>>>(A, nullptr, t.Bt, nullptr, Cf,
                                                   nullptr, N_NODES, t.K, lda, t.Nc,
                                                   ldc, t.Kp, act, NX, NYB);
    };
    auto gemm_b16 = [&](const ushort* Ab, const TW& t, const float* bias, float* Cf,
                        ushort* Cb, int lda, int ldc, int act) {
        int NX = (t.Nc + 127) / 128;
        mfma_gemm<2><<<NX * NY8, 256, 0, stream>>>(nullptr, Ab, t.Bt, bias, Cf, Cb,
                                                   N_NODES, t.K, lda, t.Nc, ldc,
                                                   t.Kp, act, NX, NYB);
    };

    // ---------------- AE branch (bf16 chain — numerically identical to fp32
    // storage since staging rounded A to bf16 anyway) ----------------
    gemm_f32(x, tw[0], be1, nullptr, aeh1b, 1000, 512, 1);      // h1
    gemm_b16(aeh1b, tw[1], be2, nullptr, aeh2b, 512, 512, 1);   // h2
    gemm_b16(aeh2b, tw[2], be3, nullptr, aeh3b, 512, 2000, 1);  // h3
    gemm_b16(aeh3b, tw[3], bz1, z1buf, nullptr, 2000, 10, 0);   // z1
    gemm_small<<<(N_NODES + 7) / 8, 256, 0, stream>>>(z1buf, Wz2, bz2, out_z,
                                                      N_NODES, 10, 10, 0);  // z
    gemm_small<<<(N_NODES + 7) / 8, 256, 0, stream>>>(out_z, Wd0, bd0, dsmall,
                                                      N_NODES, 10, 10, 1);  // d0
    gemm_f32(dsmall, tw[4], bd1, nullptr, aeh3b, 10, 2000, 1);  // d1 (h3 consumed)
    gemm_b16(aeh3b, tw[5], bd2, nullptr, aeh1b, 2000, 512, 1);  // d2 (h1 consumed)
    gemm_b16(aeh1b, tw[6], bd3, nullptr, aeh2b, 512, 512, 1);   // d3 (h2 consumed)
    gemm_b16(aeh2b, tw[7], bxb, out_xbar, nullptr, 512, 1000, 0);  // x_bar

    // ---------------- shared L0 support (h = x for ALL branches) ----------------
    // topo branches (adj, f1) share topoW1: compute sup once (bf16).
    gemm_f32(x, tw[12], nullptr, nullptr, supTopo, 1000, 500, 0);

    // ---------------- GNN branches ----------------
    struct Br {
        const int* rows; const int* cols; const float* vals;
        int w0;
        float* final_dest;
    };
    Br brs[4] = {
        {fadj_rows, fadj_cols, fadj_vals, 8, out_fea4},     // fea (precise)
        {adj_rows, adj_cols, adj_vals, 12, out_topo4},
        {f2_rows, f2_cols, f2_vals, 8, out_feadiff4},
        {f1_rows, f1_cols, f1_vals, 12, out_topodiff4},
    };

    auto bn_zero = [&](int C) {
        zero_i32<<<(C + 255) / 256, 256, 0, stream>>>((int*)ssum, C);
        zero_i32<<<(C + 255) / 256, 256, 0, stream>>>((int*)ssq, C);
    };
    auto bn_f = [&](float* t, int C) {
        bn_zero(C);
        col_stats_f<<<dim3((C + 255) / 256, 40), 256, 0, stream>>>(t, ssum, ssq, C);
        bn_apply_f<<<dim3((C + 255) / 256, N_NODES), 256, 0, stream>>>(t, ssum, ssq,
                                                                       t, C);
    };
    auto bn_bb = [&](const ushort* t, ushort* h, int C, int ldh) {
        bn_zero(C);
        col_stats<<<dim3((C + 255) / 256, 40), 256, 0, stream>>>(t, ssum, ssq, C);
        bn_apply_bb<<<dim3((C + 255) / 256, N_NODES), 256, 0, stream>>>(
            t, ssum, ssq, h, C, ldh);
    };
    auto bn_bf = [&](const ushort* t, float* h, int C) {
        bn_zero(C);
        col_stats<<<dim3((C + 255) / 256, 40), 256, 0, stream>>>(t, ssum, ssq, C);
        bn_apply<<<dim3((C + 255) / 256, N_NODES), 256, 0, stream>>>(t, ssum, ssq,
                                                                     h, C);
    };
    auto spmmA_f = [&](const float* sup, float* dst, int C) {
        spmm_act_f<<<dim3(N_NODES, (C + 255) / 256), 256, 0, stream>>>(
            sup, row_ptr, cols_s, vals_s, dst, C);
    };
    auto spmmA_bf = [&](const ushort* sup, ushort* dst, int C) {
        spmm_act_bf<<<dim3(N_NODES, (C + 511) / 512), 256, 0, stream>>>(
            sup, row_ptr, cols_s, vals_s, dst, C);
    };

    for (int b = 0; b < 4; ++b) {
        // CSR build
        zero_i32<<<(N_NODES + 255) / 256, 256, 0, stream>>>(counts, N_NODES);
        hist_kernel<<<(N_EDGES + 255) / 256, 256, 0, stream>>>(brs[b].rows, counts);
        scan_kernel<<<1, 1024, 0, stream>>>(counts, row_ptr);
        zero_i32<<<(N_NODES + 255) / 256, 256, 0, stream>>>(fillctr, N_NODES);
        fill_kernel<<<(N_EDGES + 255) / 256, 256, 0, stream>>>(
            brs[b].rows, brs[b].cols, brs[b].vals, row_ptr, fillctr, cols_s, vals_s);

        int w0 = brs[b].w0;
        if (b == 0) {
            // ---- fea branch: fp32 path, split-A GEMMs ----
            gemm_spl(x, tw[w0], supFea, 1000, 500, 0);  // L0 sup (alive thru b=2)
            spmmA_f(supFea, feah1, 500);
            bn_f(feah1, 500);
            gemm_spl(feah1, tw[w0 + 1], bufH, 500, 500, 0);  // L1 sup
            spmmA_f(bufH, feah2, 500);
            bn_f(feah2, 500);
            // L2 spmm-first
            spmm_gather_f<<<dim3(N_NODES, 2), 256, 0, stream>>>(
                feah2, row_ptr, cols_s, vals_s, bufH, 500);
            gemm_spl(bufH, tw[w0 + 2], feah3, 500, 2000, 2);
            bn_f(feah3, 2000);
            gemm_spl(feah3, tw[w0 + 3], bufH, 2000, 10, 0);  // L3 sup
            spmmA_f(bufH, brs[b].final_dest, 10);
            bn_f(brs[b].final_dest, 10);
        } else {
            // ---- bf16 branches; L0 sup precomputed/shared ----
            if (b == 2) {
                spmm_act_fb<<<dim3(N_NODES, 1), 256, 0, stream>>>(
                    supFea, row_ptr, cols_s, vals_s, bufC, 500);
            } else {
                spmmA_bf(supTopo, bufC, 500);
            }
            bn_bb(bufC, bufHb, 500, 512);
            gemm_b16(bufHb, tw[w0 + 1], nullptr, nullptr, bufB, 512, 500, 0);
            spmmA_bf(bufB, bufC, 500);
            bn_bb(bufC, bufHb, 500, 512);
            // L2 spmm-first
            spmm_gather_bf<<<dim3(N_NODES, 1), 256, 0, stream>>>(
                bufHb, row_ptr, cols_s, vals_s, bufH, 500, 512);
            gemm_f32(bufH, tw[w0 + 2], nullptr, nullptr, bufC, 500, 2000, 2);
            bn_bb(bufC, bufHb, 2000, 2000);
            gemm_b16(bufHb, tw[w0 + 3], nullptr, nullptr, bufB, 2000, 10, 0);
            spmmA_bf(bufB, bufC, 10);
            bn_bf(bufC, brs[b].final_dest, 10);
        }
    }

    // ---------------- attention fusion head ----------------
    mlp_u<<<(N_NODES + 3) / 4, 256, 0, stream>>>(feah1, feah2, feah3, out_fea4,
                                                 mlpW, mlpb, ubuf);
    zout_kernel<<<dim3(12, N_NODES), 256, 0, stream>>>(feah1, feah2, feah3, out_fea4,
                                                       ubuf, out_zout);
}

// Round 3
// 5689.574 us; speedup vs baseline: 1.8994x; 1.1065x over previous
//
#include <hip/hip_runtime.h>
#include <cstdint>
#include <cstddef>

#define N_NODES 20000
#define N_EDGES 640000

typedef short short8 __attribute__((ext_vector_type(8)));
typedef float floatx4 __attribute__((ext_vector_type(4)));

__device__ __forceinline__ ushort f2bf(float f) {
    uint32_t u = __float_as_uint(f);
    uint32_t r = (u + 0x7fff + ((u >> 16) & 1)) >> 16;
    return (ushort)r;
}
__device__ __forceinline__ float bf2f(ushort u) {
    return __uint_as_float(((uint32_t)u) << 16);
}

// ---------------------------------------------------------------- utilities
__global__ __launch_bounds__(256) void zero_i32(int* __restrict__ p, int n) {
    int i = blockIdx.x * 256 + threadIdx.x;
    if (i < n) p[i] = 0;
}

// weight pre-transpose + bf16 convert: W[K][Nc] fp32 -> Bt[Nc][Kp] bf16 (zero pad)
__global__ __launch_bounds__(256) void transpose_w(const float* __restrict__ W,
                                                   ushort* __restrict__ Bt,
                                                   int K, int Nc, int Kp) {
    int idx = blockIdx.x * 256 + threadIdx.x;
    if (idx >= Nc * Kp) return;
    int n = idx / Kp, k = idx % Kp;
    Bt[idx] = (k < K) ? f2bf(W[(size_t)k * Nc + n]) : (ushort)0;
}

// ---------------------------------------------------------------- CSR build
__global__ __launch_bounds__(256) void hist_kernel(const int* __restrict__ rows,
                                                   int* __restrict__ counts) {
    int e = blockIdx.x * 256 + threadIdx.x;
    if (e < N_EDGES) atomicAdd(&counts[rows[e]], 1);
}

__global__ __launch_bounds__(1024) void scan_kernel(const int* __restrict__ counts,
                                                    int* __restrict__ row_ptr) {
    __shared__ int part[1024];
    const int CH = 20;
    int tid = threadIdx.x;
    int t0 = tid * CH;
    int s = 0;
    for (int i = 0; i < CH; ++i) {
        int p = t0 + i;
        if (p < N_NODES) s += counts[p];
    }
    part[tid] = s;
    __syncthreads();
    for (int off = 1; off < 1024; off <<= 1) {
        int v = (tid >= off) ? part[tid - off] : 0;
        __syncthreads();
        if (tid >= off) part[tid] += v;
        __syncthreads();
    }
    int base = (tid == 0) ? 0 : part[tid - 1];
    for (int i = 0; i < CH; ++i) {
        int p = t0 + i;
        if (p < N_NODES) {
            row_ptr[p] = base;
            base += counts[p];
            if (p == N_NODES - 1) row_ptr[N_NODES] = base;
        }
    }
}

__global__ __launch_bounds__(256) void fill_kernel(const int* __restrict__ rows,
                                                   const int* __restrict__ cols,
                                                   const float* __restrict__ vals,
                                                   const int* __restrict__ row_ptr,
                                                   int* __restrict__ fillctr,
                                                   int* __restrict__ cols_s,
                                                   float* __restrict__ vals_s) {
    int e = blockIdx.x * 256 + threadIdx.x;
    if (e < N_EDGES) {
        int r = rows[e];
        int pos = atomicAdd(&fillctr[r], 1);
        int idx = row_ptr[r] + pos;
        cols_s[idx] = cols[e];
        vals_s[idx] = vals[e];
    }
}

// ---------------------------------------------------------------- MFMA GEMM
// C[M,Nc] = act(A[M,K] @ B[K,Nc] + bias).
// AMODE: 0 = fp32 A; 1 = fp32 A with hi/lo bf16 split (~fp32 accuracy);
//        2 = bf16 A (row stride lda, pad region handled by K-guard).
// B pre-transposed bf16 [Nc][Kp]. Output: Cb!=null -> bf16 else fp32 (stride ldc).
// act: 1=relu, 2=leaky(0.2)+elu.
// Grid 1-D XCD-group swizzled; register double-buffer prefetch.
template <int AMODE>
__global__ __launch_bounds__(256) void mfma_gemm(
    const float* __restrict__ A, const ushort* __restrict__ Ab,
    const ushort* __restrict__ Bt,
    const float* __restrict__ bias, float* __restrict__ Cf,
    ushort* __restrict__ Cb, int M, int K, int lda, int Nc, int ldc, int Kp,
    int act, int NX, int NY) {
    __shared__ __align__(16) ushort As[128][40];
    __shared__ __align__(16) ushort Bs[128][40];
    __shared__ __align__(16) ushort Al[(AMODE == 1) ? 128 : 1][40];

    int id = blockIdx.x;
    int r8 = id & 7, tt = id >> 3;
    int bx = tt % NX, qq = tt / NX;
    int by = r8 + 8 * qq;
    if (by >= NY) return;
    int row0 = by * 128, col0 = bx * 128;

    int tid = threadIdx.x;
    int wave = tid >> 6, lane = tid & 63;
    int wr = (wave >> 1) * 64, wc = (wave & 1) * 64;
    int m16 = lane & 15, quad = lane >> 4;

    floatx4 acc[4][4] = {};
    int KT = (K + 31) >> 5;
    bool k4 = (K & 3) == 0;

    int arf = tid >> 3, akq = (tid & 7) << 2;
    int arb = tid >> 2, akb = (tid & 3) << 3;
    int bn_ = tid >> 2, bch = (tid & 3) << 3;

    float4 avA[4], avB[4];
    uint4 abvA[2], abvB[2], bvA[2], bvB[2];

#define ISSUE_T(AV, ABV, BV, KTARG)                                          \
    do {                                                                     \
        int k0_ = (KTARG) << 5;                                              \
        if constexpr (AMODE == 2) {                                          \
            for (int p = 0; p < 2; ++p) {                                    \
                int grow = row0 + arb + p * 64;                              \
                int gk = k0_ + akb;                                          \
                uint4 z = {0u, 0u, 0u, 0u};                                  \
                if (grow < M) {                                              \
                    const ushort* ap = Ab + (size_t)grow * lda + gk;         \
                    if (gk + 7 < K) {                                        \
                        z = *(const uint4*)ap;                               \
                    } else {                                                 \
                        ushort tm[8] = {0, 0, 0, 0, 0, 0, 0, 0};             \
                        for (int j = 0; j < 8; ++j)                          \
                            if (gk + j < K) tm[j] = ap[j];                   \
                        z.x = (uint)tm[0] | ((uint)tm[1] << 16);             \
                        z.y = (uint)tm[2] | ((uint)tm[3] << 16);             \
                        z.z = (uint)tm[4] | ((uint)tm[5] << 16);             \
                        z.w = (uint)tm[6] | ((uint)tm[7] << 16);             \
                    }                                                        \
                }                                                            \
                ABV[p] = z;                                                  \
            }                                                                \
        } else {                                                             \
            for (int p = 0; p < 4; ++p) {                                    \
                int grow = row0 + arf + p * 32;                              \
                int gk = k0_ + akq;                                          \
                float4 v = {0.f, 0.f, 0.f, 0.f};                             \
                if (grow < M) {                                              \
                    const float* ap = A + (size_t)grow * lda + gk;           \
                    if (k4 && gk + 3 < K) {                                  \
                        v = *(const float4*)ap;                              \
                    } else {                                                 \
                        if (gk < K) v.x = ap[0];                             \
                        if (gk + 1 < K) v.y = ap[1];                         \
                        if (gk + 2 < K) v.z = ap[2];                         \
                        if (gk + 3 < K) v.w = ap[3];                         \
                    }                                                        \
                }                                                            \
                AV[p] = v;                                                   \
            }                                                                \
        }                                                                    \
        for (int p = 0; p < 2; ++p) {                                        \
            int gcol = col0 + bn_ + p * 64;                                  \
            uint4 z = {0u, 0u, 0u, 0u};                                      \
            if (gcol < Nc) z = *(const uint4*)&Bt[(size_t)gcol * Kp + k0_ + bch]; \
            BV[p] = z;                                                       \
        }                                                                    \
    } while (0)

#define WRITE_T(AV, ABV, BV)                                                 \
    do {                                                                     \
        if constexpr (AMODE == 2) {                                          \
            for (int p = 0; p < 2; ++p)                                      \
                *(uint4*)&As[arb + p * 64][akb] = ABV[p];                    \
        } else {                                                             \
            for (int p = 0; p < 4; ++p) {                                    \
                float4 v = AV[p];                                            \
                ushort4 hi;                                                  \
                hi.x = f2bf(v.x); hi.y = f2bf(v.y);                          \
                hi.z = f2bf(v.z); hi.w = f2bf(v.w);                          \
                *(ushort4*)&As[arf + p * 32][akq] = hi;                      \
                if constexpr (AMODE == 1) {                                  \
                    ushort4 lo;                                              \
                    lo.x = f2bf(v.x - bf2f(hi.x));                           \
                    lo.y = f2bf(v.y - bf2f(hi.y));                           \
                    lo.z = f2bf(v.z - bf2f(hi.z));                           \
                    lo.w = f2bf(v.w - bf2f(hi.w));                           \
                    *(ushort4*)&Al[arf + p * 32][akq] = lo;                  \
                }                                                            \
            }                                                                \
        }                                                                    \
        for (int p = 0; p < 2; ++p)                                          \
            *(uint4*)&Bs[bn_ + p * 64][bch] = BV[p];                         \
    } while (0)

    ISSUE_T(avA, abvA, bvA, 0);
    for (int kt = 0; kt < KT; ++kt) {
        if (kt) __syncthreads();
        if ((kt & 1) == 0) {
            WRITE_T(avA, abvA, bvA);
            if (kt + 1 < KT) ISSUE_T(avB, abvB, bvB, kt + 1);
        } else {
            WRITE_T(avB, abvB, bvB);
            if (kt + 1 < KT) ISSUE_T(avA, abvA, bvA, kt + 1);
        }
        __syncthreads();
        short8 a[4], b[4];
        int ko = quad * 8;
#pragma unroll
        for (int i = 0; i < 4; ++i) a[i] = *(short8*)&As[wr + i * 16 + m16][ko];
#pragma unroll
        for (int j = 0; j < 4; ++j) b[j] = *(short8*)&Bs[wc + j * 16 + m16][ko];
        if constexpr (AMODE == 1) {
            short8 al[4];
#pragma unroll
            for (int i = 0; i < 4; ++i) al[i] = *(short8*)&Al[wr + i * 16 + m16][ko];
#pragma unroll
            for (int i = 0; i < 4; ++i)
#pragma unroll
                for (int j = 0; j < 4; ++j)
                    acc[i][j] = __builtin_amdgcn_mfma_f32_16x16x32_bf16(
                        al[i], b[j], acc[i][j], 0, 0, 0);
        }
#pragma unroll
        for (int i = 0; i < 4; ++i)
#pragma unroll
            for (int j = 0; j < 4; ++j)
                acc[i][j] = __builtin_amdgcn_mfma_f32_16x16x32_bf16(
                    a[i], b[j], acc[i][j], 0, 0, 0);
    }
#undef ISSUE_T
#undef WRITE_T

#pragma unroll
    for (int i = 0; i < 4; ++i) {
        int rbase = row0 + wr + i * 16 + quad * 4;
#pragma unroll
        for (int j = 0; j < 4; ++j) {
            int gcol = col0 + wc + j * 16 + m16;
            if (gcol >= Nc) continue;
            float bv = bias ? bias[gcol] : 0.f;
#pragma unroll
            for (int r = 0; r < 4; ++r) {
                int grow = rbase + r;
                if (grow >= M) continue;
                float v = acc[i][j][r] + bv;
                if (act == 1) v = v > 0.f ? v : 0.f;
                else if (act == 2) v = v > 0.f ? v : (expf(0.2f * v) - 1.0f);
                if (Cb) Cb[(size_t)grow * ldc + gcol] = f2bf(v);
                else Cf[(size_t)grow * ldc + gcol] = v;
            }
        }
    }
}

// ---------------------------------------------------------------- small vector GEMM
__global__ __launch_bounds__(256) void gemm_small(
    const float* __restrict__ A, const float* __restrict__ B,
    const float* __restrict__ bias, float* __restrict__ C,
    int M, int K, int Nc, int act) {
    int row = blockIdx.x * 8 + (threadIdx.x >> 5);
    int c = threadIdx.x & 31;
    if (row >= M || c >= Nc) return;
    float acc = bias ? bias[c] : 0.f;
    for (int k = 0; k < K; ++k) acc += A[(size_t)row * K + k] * B[(size_t)k * Nc + c];
    if (act) acc = acc > 0.f ? acc : 0.f;
    C[(size_t)row * Nc + c] = acc;
}

// ---------------------------------------------------------------- SpMM gathers
// ILP-unrolled: 4 features/thread, 4 edges/iteration with independent
// accumulators -> 4x 16B (or 8B) gathers in flight per thread. Tail is a
// masked parallel batch (not a serial loop) to avoid latency-serialization.
// ACT: 0 = raw sum, 1 = leaky(0.2)+elu. OUTBF/OUTF32 pick output dtype.

// fp32 sup in
template <int ACT, int OUTBF>
__global__ __launch_bounds__(128) void spmm_f32in(
    const float* __restrict__ sup, const int* __restrict__ rp,
    const int* __restrict__ cols_s, const float* __restrict__ vals_s,
    float* __restrict__ outf, ushort* __restrict__ outb,
    int C, int ldin, int ldout) {
    int r = blockIdx.x;
    int f0 = (blockIdx.y * 128 + threadIdx.x) * 4;
    if (f0 >= C) return;
    int s = rp[r], e = rp[r + 1];
    const float* sb = sup + f0;
    floatx4 A0 = {0.f, 0.f, 0.f, 0.f}, A1 = A0, A2 = A0, A3 = A0;
    int i = s;
    for (; i + 4 <= e; i += 4) {
        int c0 = cols_s[i], c1 = cols_s[i + 1], c2 = cols_s[i + 2],
            c3 = cols_s[i + 3];
        float v0 = vals_s[i], v1 = vals_s[i + 1], v2 = vals_s[i + 2],
              v3 = vals_s[i + 3];
        floatx4 u0 = *(const floatx4*)(sb + (size_t)c0 * ldin);
        floatx4 u1 = *(const floatx4*)(sb + (size_t)c1 * ldin);
        floatx4 u2 = *(const floatx4*)(sb + (size_t)c2 * ldin);
        floatx4 u3 = *(const floatx4*)(sb + (size_t)c3 * ldin);
        A0 += v0 * u0;
        A1 += v1 * u1;
        A2 += v2 * u2;
        A3 += v3 * u3;
    }
    int n = e - i;
    if (n > 0) {
        int c0 = cols_s[i];
        int c1 = cols_s[i + (n > 1 ? 1 : 0)];
        int c2 = cols_s[i + (n > 2 ? 2 : 0)];
        float v0 = vals_s[i];
        float v1 = n > 1 ? vals_s[i + 1] : 0.f;
        float v2 = n > 2 ? vals_s[i + 2] : 0.f;
        floatx4 u0 = *(const floatx4*)(sb + (size_t)c0 * ldin);
        floatx4 u1 = *(const floatx4*)(sb + (size_t)c1 * ldin);
        floatx4 u2 = *(const floatx4*)(sb + (size_t)c2 * ldin);
        A0 += v0 * u0;
        A1 += v1 * u1;
        A2 += v2 * u2;
    }
    floatx4 acc = (A0 + A1) + (A2 + A3);
    if (ACT) {
#pragma unroll
        for (int k = 0; k < 4; ++k)
            acc[k] = acc[k] > 0.f ? acc[k] : (expf(0.2f * acc[k]) - 1.0f);
    }
    if (OUTBF) {
        ushort4 w;
        w.x = f2bf(acc[0]); w.y = f2bf(acc[1]);
        w.z = f2bf(acc[2]); w.w = f2bf(acc[3]);
        *(ushort4*)&outb[(size_t)r * ldout + f0] = w;
    } else {
        *(floatx4*)&outf[(size_t)r * ldout + f0] = acc;
    }
}

// bf16 sup in
template <int ACT, int OUTF32>
__global__ __launch_bounds__(128) void spmm_bf16in(
    const ushort* __restrict__ sup, const int* __restrict__ rp,
    const int* __restrict__ cols_s, const float* __restrict__ vals_s,
    float* __restrict__ outf, ushort* __restrict__ outb,
    int C, int ldin, int ldout) {
    int r = blockIdx.x;
    int f0 = (blockIdx.y * 128 + threadIdx.x) * 4;
    if (f0 >= C) return;
    int s = rp[r], e = rp[r + 1];
    const ushort* sb = sup + f0;
    floatx4 A0 = {0.f, 0.f, 0.f, 0.f}, A1 = A0, A2 = A0, A3 = A0;
    int i = s;
#define UNPK(ACCV, VV, QQ)                                                   \
    do {                                                                     \
        ACCV[0] += VV * bf2f((ushort)(QQ.x & 0xffff));                       \
        ACCV[1] += VV * bf2f((ushort)(QQ.x >> 16));                          \
        ACCV[2] += VV * bf2f((ushort)(QQ.y & 0xffff));                       \
        ACCV[3] += VV * bf2f((ushort)(QQ.y >> 16));                          \
    } while (0)
    for (; i + 4 <= e; i += 4) {
        int c0 = cols_s[i], c1 = cols_s[i + 1], c2 = cols_s[i + 2],
            c3 = cols_s[i + 3];
        float v0 = vals_s[i], v1 = vals_s[i + 1], v2 = vals_s[i + 2],
              v3 = vals_s[i + 3];
        uint2 q0 = *(const uint2*)(sb + (size_t)c0 * ldin);
        uint2 q1 = *(const uint2*)(sb + (size_t)c1 * ldin);
        uint2 q2 = *(const uint2*)(sb + (size_t)c2 * ldin);
        uint2 q3 = *(const uint2*)(sb + (size_t)c3 * ldin);
        UNPK(A0, v0, q0);
        UNPK(A1, v1, q1);
        UNPK(A2, v2, q2);
        UNPK(A3, v3, q3);
    }
    int n = e - i;
    if (n > 0) {
        int c0 = cols_s[i];
        int c1 = cols_s[i + (n > 1 ? 1 : 0)];
        int c2 = cols_s[i + (n > 2 ? 2 : 0)];
        float v0 = vals_s[i];
        float v1 = n > 1 ? vals_s[i + 1] : 0.f;
        float v2 = n > 2 ? vals_s[i + 2] : 0.f;
        uint2 q0 = *(const uint2*)(sb + (size_t)c0 * ldin);
        uint2 q1 = *(const uint2*)(sb + (size_t)c1 * ldin);
        uint2 q2 = *(const uint2*)(sb + (size_t)c2 * ldin);
        UNPK(A0, v0, q0);
        UNPK(A1, v1, q1);
        UNPK(A2, v2, q2);
    }
#undef UNPK
    floatx4 acc = (A0 + A1) + (A2 + A3);
    if (ACT) {
#pragma unroll
        for (int k = 0; k < 4; ++k)
            acc[k] = acc[k] > 0.f ? acc[k] : (expf(0.2f * acc[k]) - 1.0f);
    }
    if (OUTF32) {
        *(floatx4*)&outf[(size_t)r * ldout + f0] = acc;
    } else {
        ushort4 w;
        w.x = f2bf(acc[0]); w.y = f2bf(acc[1]);
        w.z = f2bf(acc[2]); w.w = f2bf(acc[3]);
        *(ushort4*)&outb[(size_t)r * ldout + f0] = w;
    }
}

// small-C (C<=16) spmm+act: one row/block, 16 edge-substreams x 16 lanes,
// LDS reduce. 16x edge-level parallelism vs the serial per-lane loop.
__global__ __launch_bounds__(256) void spmm_small_bf(
    const ushort* __restrict__ sup, const int* __restrict__ rp,
    const int* __restrict__ cols_s, const float* __restrict__ vals_s,
    ushort* __restrict__ t, int C, int ldin) {
    __shared__ float red[16][17];
    int r = blockIdx.x;
    int f = threadIdx.x & 15, sub = threadIdx.x >> 4;
    int s = rp[r], e = rp[r + 1];
    float acc = 0.f;
    if (f < C) {
        for (int i = s + sub; i < e; i += 16)
            acc += vals_s[i] * bf2f(sup[(size_t)cols_s[i] * ldin + f]);
    }
    red[sub][f] = acc;
    __syncthreads();
    if (sub == 0 && f < C) {
        float a = 0.f;
#pragma unroll
        for (int k = 0; k < 16; ++k) a += red[k][f];
        float o = a > 0.f ? a : (expf(0.2f * a) - 1.0f);
        t[(size_t)r * C + f] = f2bf(o);
    }
}

__global__ __launch_bounds__(256) void spmm_small_f(
    const float* __restrict__ sup, const int* __restrict__ rp,
    const int* __restrict__ cols_s, const float* __restrict__ vals_s,
    float* __restrict__ t, int C, int ldin) {
    __shared__ float red[16][17];
    int r = blockIdx.x;
    int f = threadIdx.x & 15, sub = threadIdx.x >> 4;
    int s = rp[r], e = rp[r + 1];
    float acc = 0.f;
    if (f < C) {
        for (int i = s + sub; i < e; i += 16)
            acc += vals_s[i] * sup[(size_t)cols_s[i] * ldin + f];
    }
    red[sub][f] = acc;
    __syncthreads();
    if (sub == 0 && f < C) {
        float a = 0.f;
#pragma unroll
        for (int k = 0; k < 16; ++k) a += red[k][f];
        t[(size_t)r * C + f] = a > 0.f ? a : (expf(0.2f * a) - 1.0f);
    }
}

// ---------------------------------------------------------------- BatchNorm (bf16 t)
__global__ __launch_bounds__(256) void col_stats(const ushort* __restrict__ t,
                                                 float* __restrict__ sum,
                                                 float* __restrict__ sumsq, int C,
                                                 int rpb) {
    int c = blockIdx.x * 256 + threadIdx.x;
    int r0 = blockIdx.y * rpb;
    if (c >= C) return;
    float s = 0.f, ss = 0.f;
    for (int r = r0; r < r0 + rpb; ++r) {
        float v = bf2f(t[(size_t)r * C + c]);
        s += v;
        ss += v * v;
    }
    atomicAdd(&sum[c], s);
    atomicAdd(&sumsq[c], ss);
}

__global__ __launch_bounds__(256) void bn_apply(const ushort* __restrict__ t,
                                                const float* __restrict__ sum,
                                                const float* __restrict__ sumsq,
                                                float* __restrict__ h, int C) {
    int c = blockIdx.x * 256 + threadIdx.x;
    int r = blockIdx.y;
    if (c >= C) return;
    float mean = sum[c] * (1.0f / N_NODES);
    float var = sumsq[c] * (1.0f / N_NODES) - mean * mean;
    float rs = rsqrtf(var + 1e-5f);
    h[(size_t)r * C + c] = (bf2f(t[(size_t)r * C + c]) - mean) * rs;
}

__global__ __launch_bounds__(256) void bn_apply_bb(const ushort* __restrict__ t,
                                                   const float* __restrict__ sum,
                                                   const float* __restrict__ sumsq,
                                                   ushort* __restrict__ h, int C,
                                                   int ldh) {
    int c = blockIdx.x * 256 + threadIdx.x;
    int r = blockIdx.y;
    if (c >= C) return;
    float mean = sum[c] * (1.0f / N_NODES);
    float var = sumsq[c] * (1.0f / N_NODES) - mean * mean;
    float rs = rsqrtf(var + 1e-5f);
    h[(size_t)r * ldh + c] = f2bf((bf2f(t[(size_t)r * C + c]) - mean) * rs);
}

// element-parallel small-C variants
__global__ __launch_bounds__(256) void bn_elem_bf(const ushort* __restrict__ t,
                                                  const float* __restrict__ sum,
                                                  const float* __restrict__ sumsq,
                                                  float* __restrict__ h, int C,
                                                  int total) {
    int idx = blockIdx.x * 256 + threadIdx.x;
    if (idx >= total) return;
    int c = idx % C;
    float mean = sum[c] * (1.0f / N_NODES);
    float var = sumsq[c] * (1.0f / N_NODES) - mean * mean;
    float rs = rsqrtf(var + 1e-5f);
    h[idx] = (bf2f(t[idx]) - mean) * rs;
}

__global__ __launch_bounds__(256) void bn_elem_f(float* __restrict__ t,
                                                 const float* __restrict__ sum,
                                                 const float* __restrict__ sumsq,
                                                 int C, int total) {
    int idx = blockIdx.x * 256 + threadIdx.x;
    if (idx >= total) return;
    int c = idx % C;
    float mean = sum[c] * (1.0f / N_NODES);
    float var = sumsq[c] * (1.0f / N_NODES) - mean * mean;
    float rs = rsqrtf(var + 1e-5f);
    t[idx] = (t[idx] - mean) * rs;
}

// ---------------------------------------------------------------- BatchNorm (fp32)
__global__ __launch_bounds__(256) void col_stats_f(const float* __restrict__ t,
                                                   float* __restrict__ sum,
                                                   float* __restrict__ sumsq, int C,
                                                   int rpb) {
    int c = blockIdx.x * 256 + threadIdx.x;
    int r0 = blockIdx.y * rpb;
    if (c >= C) return;
    float s = 0.f, ss = 0.f;
    for (int r = r0; r < r0 + rpb; ++r) {
        float v = t[(size_t)r * C + c];
        s += v;
        ss += v * v;
    }
    atomicAdd(&sum[c], s);
    atomicAdd(&sumsq[c], ss);
}

__global__ __launch_bounds__(256) void bn_apply_f(const float* __restrict__ t,
                                                  const float* __restrict__ sum,
                                                  const float* __restrict__ sumsq,
                                                  float* __restrict__ h, int C) {
    int c = blockIdx.x * 256 + threadIdx.x;
    int r = blockIdx.y;
    if (c >= C) return;
    float mean = sum[c] * (1.0f / N_NODES);
    float var = sumsq[c] * (1.0f / N_NODES) - mean * mean;
    float rs = rsqrtf(var + 1e-5f);
    h[(size_t)r * C + c] = (t[(size_t)r * C + c] - mean) * rs;
}

// ---------------------------------------------------------------- attention head
__global__ __launch_bounds__(256) void mlp_u(const float* __restrict__ h1,
                                             const float* __restrict__ h2,
                                             const float* __restrict__ h3,
                                             const float* __restrict__ h4,
                                             const float* __restrict__ W,
                                             const float* __restrict__ b,
                                             float* __restrict__ u) {
    int lane = threadIdx.x & 63;
    int wv = threadIdx.x >> 6;
    int row = blockIdx.x * 4 + wv;
    if (row >= N_NODES) return;
    float acc[5] = {0.f, 0.f, 0.f, 0.f, 0.f};
    const float* hs[4] = {h1, h2, h3, h4};
    const int Cs[4] = {500, 500, 2000, 10};
    const int Woff[4] = {0, 500, 1000, 3000};
    for (int sg = 0; sg < 4; ++sg) {
        const float* hp = hs[sg] + (size_t)row * Cs[sg];
        const float* wp = W + (size_t)Woff[sg] * 5;
        for (int k = lane; k < Cs[sg]; k += 64) {
            float a = hp[k];
#pragma unroll
            for (int j = 0; j < 5; ++j) acc[j] += a * wp[k * 5 + j];
        }
    }
#pragma unroll
    for (int j = 0; j < 5; ++j)
        for (int off = 32; off > 0; off >>= 1) acc[j] += __shfl_down(acc[j], off, 64);
    if (lane == 0) {
        float t[5], m = -1e30f;
#pragma unroll
        for (int j = 0; j < 5; ++j) {
            t[j] = tanhf(acc[j] + b[j]);
            m = fmaxf(m, t[j]);
        }
        float s = 0.f;
#pragma unroll
        for (int j = 0; j < 5; ++j) {
            t[j] = expf(t[j] - m);
            s += t[j];
        }
        float inv = 1.0f / s;
        float n2 = 0.f;
#pragma unroll
        for (int j = 0; j < 5; ++j) {
            t[j] *= inv;
            n2 += t[j] * t[j];
        }
        float nrm = fmaxf(sqrtf(n2), 1e-12f);
        float innrm = 1.0f / nrm;
#pragma unroll
        for (int j = 0; j < 5; ++j) u[(size_t)row * 5 + j] = t[j] * innrm;
    }
}

__global__ __launch_bounds__(256) void zout_kernel(const float* __restrict__ h1,
                                                   const float* __restrict__ h2,
                                                   const float* __restrict__ h3,
                                                   const float* __restrict__ h4,
                                                   const float* __restrict__ u,
                                                   float* __restrict__ out) {
    int c = blockIdx.x * 256 + threadIdx.x;
    int row = blockIdx.y;
    if (c >= 3010) return;
    int seg, cl;
    const float* hp;
    if (c < 500)       { seg = 0; cl = c;        hp = h1 + (size_t)row * 500; }
    else if (c < 1000) { seg = 1; cl = c - 500;  hp = h2 + (size_t)row * 500; }
    else if (c < 3000) { seg = 2; cl = c - 1000; hp = h3 + (size_t)row * 2000; }
    else               { seg = 3; cl = c - 3000; hp = h4 + (size_t)row * 10; }
    out[(size_t)row * 3010 + c] = u[(size_t)row * 5 + seg] * hp[cl];
}

// ---------------------------------------------------------------- launch
extern "C" void kernel_launch(void* const* d_in, const int* in_sizes, int n_in,
                              void* d_out, int out_size, void* d_ws, size_t ws_size,
                              hipStream_t stream) {
    const float* x = (const float*)d_in[0];
    const int* adj_rows  = (const int*)d_in[1];
    const int* adj_cols  = (const int*)d_in[2];
    const float* adj_vals = (const float*)d_in[3];
    const int* fadj_rows = (const int*)d_in[4];
    const int* fadj_cols = (const int*)d_in[5];
    const float* fadj_vals = (const float*)d_in[6];
    const int* f1_rows = (const int*)d_in[7];
    const int* f1_cols = (const int*)d_in[8];
    const float* f1_vals = (const float*)d_in[9];
    const int* f2_rows = (const int*)d_in[10];
    const int* f2_cols = (const int*)d_in[11];
    const float* f2_vals = (const float*)d_in[12];
    const float* feaW[4]  = {(const float*)d_in[13], (const float*)d_in[14],
                             (const float*)d_in[15], (const float*)d_in[16]};
    const float* topoW[4] = {(const float*)d_in[17], (const float*)d_in[18],
                             (const float*)d_in[19], (const float*)d_in[20]};
    const float* We1 = (const float*)d_in[21]; const float* be1 = (const float*)d_in[22];
    const float* We2 = (const float*)d_in[23]; const float* be2 = (const float*)d_in[24];
    const float* We3 = (const float*)d_in[25]; const float* be3 = (const float*)d_in[26];
    const float* Wz1 = (const float*)d_in[27]; const float* bz1 = (const float*)d_in[28];
    const float* Wz2 = (const float*)d_in[29]; const float* bz2 = (const float*)d_in[30];
    const float* Wd0 = (const float*)d_in[31]; const float* bd0 = (const float*)d_in[32];
    const float* Wd1 = (const float*)d_in[33]; const float* bd1 = (const float*)d_in[34];
    const float* Wd2 = (const float*)d_in[35]; const float* bd2 = (const float*)d_in[36];
    const float* Wd3 = (const float*)d_in[37]; const float* bd3 = (const float*)d_in[38];
    const float* Wxb = (const float*)d_in[39]; const float* bxb = (const float*)d_in[40];
    const float* mlpW = (const float*)d_in[41]; const float* mlpb = (const float*)d_in[42];

    float* out = (float*)d_out;
    float* out_xbar = out;                    // [20000,1000]
    float* out_z = out + 20000000;            // [20000,10]
    float* out_fea4 = out + 20200000;
    float* out_topo4 = out + 20400000;
    float* out_feadiff4 = out + 20600000;
    float* out_topodiff4 = out + 20800000;
    float* out_zout = out + 21000000;         // [20000,3010]

    char* w = (char*)d_ws;
    auto alloc = [&](size_t bytes) -> char* {
        char* p = w;
        w += (bytes + 255) & ~(size_t)255;
        return p;
    };
    ushort* bufB = (ushort*)alloc((size_t)N_NODES * 2000 * 2);  // sup / AE h3,d1 (bf16)
    ushort* bufC = (ushort*)alloc((size_t)N_NODES * 2000 * 2);  // t / AE h1,h2,d2,d3
    float* feah1 = (float*)alloc((size_t)N_NODES * 500 * 4);
    float* feah2 = (float*)alloc((size_t)N_NODES * 500 * 4);
    float* feah3 = (float*)alloc((size_t)N_NODES * 2000 * 4);
    float* bufH  = (float*)alloc((size_t)N_NODES * 2000 * 4);   // 160 MB, partitioned:
    // [0,40MB): fp32 sup/agg scratch (C<=500)
    // [40,120MB): bufHb — bf16 h for branches 1-3 (stride 512 @C=500, 2000 @C=2000)
    // [120,160MB): supFea — fea/f2 shared fp32 L0 support (20000x500)
    ushort* bufHb = (ushort*)(bufH + 10000000);
    float* supFea = bufH + 30000000;
    float* z1buf = (float*)alloc((size_t)N_NODES * 10 * 4);
    float* dsmall = (float*)alloc((size_t)N_NODES * 10 * 4);
    float* ubuf  = (float*)alloc((size_t)N_NODES * 5 * 4);
    float* ssum  = (float*)alloc(2000 * 4);
    float* ssq   = (float*)alloc(2000 * 4);
    int* counts  = (int*)alloc(N_NODES * 4);
    int* fillctr = (int*)alloc(N_NODES * 4);
    int* row_ptr = (int*)alloc((N_NODES + 1) * 4);
    int* cols_s  = (int*)alloc((size_t)N_EDGES * 4);
    float* vals_s = (float*)alloc((size_t)N_EDGES * 4);
    ushort* supTopo = (ushort*)alloc((size_t)N_NODES * 500 * 2);  // shared topo L0 sup

    // AE bf16 intermediates aliased into bufB/bufC (free during AE phase)
    ushort* aeh1b = bufC;                       // 20000x500 @ldc 512
    ushort* aeh2b = bufC + (size_t)N_NODES * 512;
    ushort* aeh3b = bufB;                       // 20000x2000

    auto kpad = [](int K) { return ((K + 31) / 32) * 32; };
    struct TW { const float* W; int K, Nc, Kp; ushort* Bt; };
    TW tw[16] = {
        {We1, 1000, 500, 1024, nullptr}, {We2, 500, 500, 512, nullptr},
        {We3, 500, 2000, 512, nullptr},  {Wz1, 2000, 10, 2016, nullptr},
        {Wd1, 10, 2000, 32, nullptr},    {Wd2, 2000, 500, 2016, nullptr},
        {Wd3, 500, 500, 512, nullptr},   {Wxb, 500, 1000, 512, nullptr},
        {feaW[0], 1000, 500, 1024, nullptr}, {feaW[1], 500, 500, 512, nullptr},
        {feaW[2], 500, 2000, 512, nullptr},  {feaW[3], 2000, 10, 2016, nullptr},
        {topoW[0], 1000, 500, 1024, nullptr}, {topoW[1], 500, 500, 512, nullptr},
        {topoW[2], 500, 2000, 512, nullptr},  {topoW[3], 2000, 10, 2016, nullptr},
    };
    for (int i = 0; i < 16; ++i) {
        tw[i].Kp = kpad(tw[i].K);
        tw[i].Bt = (ushort*)alloc((size_t)tw[i].Nc * tw[i].Kp * 2);
        int tot = tw[i].Nc * tw[i].Kp;
        transpose_w<<<(tot + 255) / 256, 256, 0, stream>>>(
            tw[i].W, tw[i].Bt, tw[i].K, tw[i].Nc, tw[i].Kp);
    }

    const int NYB = (N_NODES + 127) / 128;            // 157
    const int NY8 = 8 * ((NYB + 7) / 8);              // 160 swizzle slots
    auto gemm_f32 = [&](const float* A, const TW& t, const float* bias, float* Cf,
                        ushort* Cb, int lda, int ldc, int act) {
        int NX = (t.Nc + 127) / 128;
        mfma_gemm<0><<<NX * NY8, 256, 0, stream>>>(A, nullptr, t.Bt, bias, Cf, Cb,
                                                   N_NODES, t.K, lda, t.Nc, ldc,
                                                   t.Kp, act, NX, NYB);
    };
    auto gemm_spl = [&](const float* A, const TW& t, float* Cf, int lda, int ldc,
                        int act) {
        int NX = (t.Nc + 127) / 128;
        mfma_gemm<1><<<NX * NY8, 256, 0, stream>>>(A, nullptr, t.Bt, nullptr, Cf,
                                                   nullptr, N_NODES, t.K, lda, t.Nc,
                                                   ldc, t.Kp, act, NX, NYB);
    };
    auto gemm_b16 = [&](const ushort* Ab, const TW& t, const float* bias, float* Cf,
                        ushort* Cb, int lda, int ldc, int act) {
        int NX = (t.Nc + 127) / 128;
        mfma_gemm<2><<<NX * NY8, 256, 0, stream>>>(nullptr, Ab, t.Bt, bias, Cf, Cb,
                                                   N_NODES, t.K, lda, t.Nc, ldc,
                                                   t.Kp, act, NX, NYB);
    };

    // ---------------- AE branch ----------------
    gemm_f32(x, tw[0], be1, nullptr, aeh1b, 1000, 512, 1);      // h1
    gemm_b16(aeh1b, tw[1], be2, nullptr, aeh2b, 512, 512, 1);   // h2
    gemm_b16(aeh2b, tw[2], be3, nullptr, aeh3b, 512, 2000, 1);  // h3
    gemm_b16(aeh3b, tw[3], bz1, z1buf, nullptr, 2000, 10, 0);   // z1
    gemm_small<<<(N_NODES + 7) / 8, 256, 0, stream>>>(z1buf, Wz2, bz2, out_z,
                                                      N_NODES, 10, 10, 0);  // z
    gemm_small<<<(N_NODES + 7) / 8, 256, 0, stream>>>(out_z, Wd0, bd0, dsmall,
                                                      N_NODES, 10, 10, 1);  // d0
    gemm_f32(dsmall, tw[4], bd1, nullptr, aeh3b, 10, 2000, 1);  // d1 (h3 consumed)
    gemm_b16(aeh3b, tw[5], bd2, nullptr, aeh1b, 2000, 512, 1);  // d2 (h1 consumed)
    gemm_b16(aeh1b, tw[6], bd3, nullptr, aeh2b, 512, 512, 1);   // d3 (h2 consumed)
    gemm_b16(aeh2b, tw[7], bxb, out_xbar, nullptr, 512, 1000, 0);  // x_bar

    // ---------------- shared L0 supports ----------------
    gemm_f32(x, tw[12], nullptr, nullptr, supTopo, 1000, 500, 0);

    struct Br {
        const int* rows; const int* cols; const float* vals;
        int w0;
        float* final_dest;
    };
    Br brs[4] = {
        {fadj_rows, fadj_cols, fadj_vals, 8, out_fea4},     // fea (precise)
        {adj_rows, adj_cols, adj_vals, 12, out_topo4},
        {f2_rows, f2_cols, f2_vals, 8, out_feadiff4},
        {f1_rows, f1_cols, f1_vals, 12, out_topodiff4},
    };

    auto bn_zero = [&](int C) {
        zero_i32<<<(C + 255) / 256, 256, 0, stream>>>((int*)ssum, C);
        zero_i32<<<(C + 255) / 256, 256, 0, stream>>>((int*)ssq, C);
    };
    auto bn_f = [&](float* t, int C) {
        bn_zero(C);
        if (C <= 16) {
            col_stats_f<<<dim3(1, 200), 256, 0, stream>>>(t, ssum, ssq, C, 100);
            int tot = N_NODES * C;
            bn_elem_f<<<(tot + 255) / 256, 256, 0, stream>>>(t, ssum, ssq, C, tot);
        } else {
            col_stats_f<<<dim3((C + 255) / 256, 100), 256, 0, stream>>>(
                t, ssum, ssq, C, 200);
            bn_apply_f<<<dim3((C + 255) / 256, N_NODES), 256, 0, stream>>>(
                t, ssum, ssq, t, C);
        }
    };
    auto bn_bb = [&](const ushort* t, ushort* h, int C, int ldh) {
        bn_zero(C);
        col_stats<<<dim3((C + 255) / 256, 100), 256, 0, stream>>>(t, ssum, ssq, C,
                                                                  200);
        bn_apply_bb<<<dim3((C + 255) / 256, N_NODES), 256, 0, stream>>>(
            t, ssum, ssq, h, C, ldh);
    };
    auto bn_bf_small = [&](const ushort* t, float* h, int C) {  // C<=16
        bn_zero(C);
        col_stats<<<dim3(1, 200), 256, 0, stream>>>(t, ssum, ssq, C, 100);
        int tot = N_NODES * C;
        bn_elem_bf<<<(tot + 255) / 256, 256, 0, stream>>>(t, ssum, ssq, h, C, tot);
    };

    for (int b = 0; b < 4; ++b) {
        // CSR build
        zero_i32<<<(N_NODES + 255) / 256, 256, 0, stream>>>(counts, N_NODES);
        hist_kernel<<<(N_EDGES + 255) / 256, 256, 0, stream>>>(brs[b].rows, counts);
        scan_kernel<<<1, 1024, 0, stream>>>(counts, row_ptr);
        zero_i32<<<(N_NODES + 255) / 256, 256, 0, stream>>>(fillctr, N_NODES);
        fill_kernel<<<(N_EDGES + 255) / 256, 256, 0, stream>>>(
            brs[b].rows, brs[b].cols, brs[b].vals, row_ptr, fillctr, cols_s, vals_s);

        int w0 = brs[b].w0;
        if (b == 0) {
            // ---- fea branch: fp32 path, split-A GEMMs ----
            gemm_spl(x, tw[w0], supFea, 1000, 500, 0);  // L0 sup (alive thru b=2)
            spmm_f32in<1, 0><<<dim3(N_NODES, 1), 128, 0, stream>>>(
                supFea, row_ptr, cols_s, vals_s, feah1, nullptr, 500, 500, 500);
            bn_f(feah1, 500);
            gemm_spl(feah1, tw[w0 + 1], bufH, 500, 500, 0);  // L1 sup
            spmm_f32in<1, 0><<<dim3(N_NODES, 1), 128, 0, stream>>>(
                bufH, row_ptr, cols_s, vals_s, feah2, nullptr, 500, 500, 500);
            bn_f(feah2, 500);
            // L2 spmm-first
            spmm_f32in<0, 0><<<dim3(N_NODES, 1), 128, 0, stream>>>(
                feah2, row_ptr, cols_s, vals_s, bufH, nullptr, 500, 500, 500);
            gemm_spl(bufH, tw[w0 + 2], feah3, 500, 2000, 2);
            bn_f(feah3, 2000);
            gemm_spl(feah3, tw[w0 + 3], bufH, 2000, 10, 0);  // L3 sup
            spmm_small_f<<<N_NODES, 256, 0, stream>>>(bufH, row_ptr, cols_s, vals_s,
                                                      brs[b].final_dest, 10, 10);
            bn_f(brs[b].final_dest, 10);
        } else {
            // ---- bf16 branches; L0 sup precomputed/shared ----
            if (b == 2) {
                spmm_f32in<1, 1><<<dim3(N_NODES, 1), 128, 0, stream>>>(
                    supFea, row_ptr, cols_s, vals_s, nullptr, bufC, 500, 500, 500);
            } else {
                spmm_bf16in<1, 0><<<dim3(N_NODES, 1), 128, 0, stream>>>(
                    supTopo, row_ptr, cols_s, vals_s, nullptr, bufC, 500, 500, 500);
            }
            bn_bb(bufC, bufHb, 500, 512);
            gemm_b16(bufHb, tw[w0 + 1], nullptr, nullptr, bufB, 512, 500, 0);
            spmm_bf16in<1, 0><<<dim3(N_NODES, 1), 128, 0, stream>>>(
                bufB, row_ptr, cols_s, vals_s, nullptr, bufC, 500, 500, 500);
            bn_bb(bufC, bufHb, 500, 512);
            // L2 spmm-first
            spmm_bf16in<0, 1><<<dim3(N_NODES, 1), 128, 0, stream>>>(
                bufHb, row_ptr, cols_s, vals_s, bufH, nullptr, 500, 512, 500);
            gemm_f32(bufH, tw[w0 + 2], nullptr, nullptr, bufC, 500, 2000, 2);
            bn_bb(bufC, bufHb, 2000, 2000);
            gemm_b16(bufHb, tw[w0 + 3], nullptr, nullptr, bufB, 2000, 10, 0);
            spmm_small_bf<<<N_NODES, 256, 0, stream>>>(bufB, row_ptr, cols_s, vals_s,
                                                       bufC, 10, 10);
            bn_bf_small(bufC, brs[b].final_dest, 10);
        }
    }

    // ---------------- attention fusion head ----------------
    mlp_u<<<(N_NODES + 3) / 4, 256, 0, stream>>>(feah1, feah2, feah3, out_fea4,
                                                 mlpW, mlpb, ubuf);
    zout_kernel<<<dim3(12, N_NODES), 256, 0, stream>>>(feah1, feah2, feah3, out_fea4,
                                                       ubuf, out_zout);
}